// Round 8
// baseline (1043.632 us; speedup 1.0000x reference)
//
#include <hip/hip_runtime.h>
#include <hip/hip_bf16.h>
#include <math.h>

#define NN 50000
#define NE 800000
#define NG 256
#define FHH 128
#define NL 6
#define NCH 49    // ceil(50000/1024)
#define NB 391    // ceil(50000/128) row-blocks

typedef __attribute__((ext_vector_type(8))) short s16x8;
typedef __attribute__((ext_vector_type(4))) float f32x4;

#define QSCALE 0.36067376022224085f   // 0.25 * log2(e)

__device__ __forceinline__ ushort f2bf(float x) {
  uint u = __float_as_uint(x);
  u += 0x7fffu + ((u >> 16) & 1u);
  return (ushort)(u >> 16);
}
__device__ __forceinline__ float bf2f(ushort h) {
  return __uint_as_float(((uint)h) << 16);
}
__device__ __forceinline__ float bfl(uint u) { return __uint_as_float(u << 16); }
__device__ __forceinline__ float bfh(uint u) { return __uint_as_float(u & 0xffff0000u); }

__device__ __forceinline__ void gload16(const ushort* g, ushort* l) {
  __builtin_amdgcn_global_load_lds(
      (const __attribute__((address_space(1))) uint*)(const void*)g,
      (__attribute__((address_space(3))) uint*)(void*)l, 16, 0, 0);
}

// ---------------- graph-boundary search (batch_vec sorted) ----------------
__global__ void k_gstart(const int* __restrict__ bv, int* __restrict__ gstart) {
  int g = blockIdx.x * blockDim.x + threadIdx.x;
  if (g > NG) return;
  int lo = 0, hi = NN;
  while (lo < hi) { int mid = (lo + hi) >> 1; if (bv[mid] < g) lo = mid + 1; else hi = mid; }
  gstart[g] = lo;
}

// ---------------- CSR build (by dst) ----------------
__global__ void k_deg(const int* __restrict__ dstv, int* __restrict__ deg) {
  int e = blockIdx.x * blockDim.x + threadIdx.x;
  if (e < NE) atomicAdd(&deg[dstv[e]], 1);
}

__global__ __launch_bounds__(256) void k_scanA(const int* __restrict__ deg, int* __restrict__ part) {
  int b = blockIdx.x, t = threadIdx.x;
  int s = 0;
  for (int j = t; j < 1024; j += 256) { int i = b * 1024 + j; if (i < NN) s += deg[i]; }
  __shared__ int sh[4];
  for (int o = 32; o; o >>= 1) s += __shfl_down(s, o, 64);
  if ((t & 63) == 0) sh[t >> 6] = s;
  __syncthreads();
  if (t == 0) part[b] = sh[0] + sh[1] + sh[2] + sh[3];
}

__global__ void k_scanB(int* __restrict__ part, int* __restrict__ row_ptr) {
  if (threadIdx.x == 0 && blockIdx.x == 0) {
    int run = 0;
    for (int i = 0; i < NCH; ++i) { int v = part[i]; part[i] = run; run += v; }
    row_ptr[NN] = run;
  }
}

__global__ __launch_bounds__(1024) void k_scanC(const int* __restrict__ deg, const int* __restrict__ part,
                                                int* __restrict__ row_ptr, int* __restrict__ cursor) {
  __shared__ int buf[1024];
  int b = blockIdx.x, t = threadIdx.x;
  int i = b * 1024 + t;
  int v = (i < NN) ? deg[i] : 0;
  buf[t] = v;
  __syncthreads();
  for (int off = 1; off < 1024; off <<= 1) {
    int add = (t >= off) ? buf[t - off] : 0;
    __syncthreads();
    buf[t] += add;
    __syncthreads();
  }
  if (i < NN) { int ex = part[b] + buf[t] - v; row_ptr[i] = ex; cursor[i] = ex; }
}

// col stores BYTE offsets of kv rows (src * 512)
__global__ void k_scatter(const int* __restrict__ srcv, const int* __restrict__ dstv,
                          int* __restrict__ cursor, uint* __restrict__ colb) {
  int e = blockIdx.x * blockDim.x + threadIdx.x;
  if (e < NE) {
    int d = dstv[e];
    int pos = atomicAdd(&cursor[d], 1);
    colb[pos] = ((uint)srcv[e]) << 9;
  }
}

// ---------------- weight preconvert: fragment-order tiles ----------------
__device__ __forceinline__ size_t wtile_idx(int k, int c) {
  return (size_t)(k >> 5) * 4096 + ((((c >> 4) * 4 + ((k & 31) >> 3)) * 16 + (c & 15)) * 8 + (k & 7));
}

__global__ __launch_bounds__(256) void k_wconv0(const float* __restrict__ W0, const float* __restrict__ W1,
                                                const float* __restrict__ W2, const float* __restrict__ W3,
                                                ushort* __restrict__ wh, ushort* __restrict__ wl) {
  int id = blockIdx.x * 256 + threadIdx.x;           // 4*64*128 = 32768
  if (id >= 4 * 64 * 128) return;
  int mat = id >> 13, rem = id & 8191;
  int k = rem >> 7, c = rem & 127;
  const float* W = (mat == 0) ? W0 : (mat == 1) ? W1 : (mat == 2) ? W2 : W3;
  float v = W[k * 128 + c];
  ushort h = f2bf(v);
  ushort lo = f2bf(v - bf2f(h));
  size_t dst = (size_t)mat * 8192 + wtile_idx(k, c);
  wh[dst] = h; wl[dst] = lo;
}

__global__ __launch_bounds__(256) void k_wconvS(const float* __restrict__ Wq, const float* __restrict__ Wk,
                                                const float* __restrict__ Wv, const float* __restrict__ Ws,
                                                ushort* __restrict__ wh, ushort* __restrict__ wl) {
  int id = blockIdx.x * 256 + threadIdx.x;           // 5*4*128*128 = 327680
  if (id >= 5 * 4 * 16384) return;
  int lay = id / 65536, rem = id % 65536;
  int mat = rem >> 14, rem2 = rem & 16383;
  int k = rem2 >> 7, c = rem2 & 127;
  const float* W = (mat == 0) ? Wq : (mat == 1) ? Wk : (mat == 2) ? Wv : Ws;
  float v = W[(size_t)lay * 16384 + k * 128 + c];
  ushort h = f2bf(v);
  ushort lo = f2bf(v - bf2f(h));
  size_t dst = 32768 + ((size_t)lay * 4 + mat) * 16384 + wtile_idx(k, c);
  wh[dst] = h; wl[dst] = lo;
}

// ---------------- presplit (layer-0 input only): split-bf16, fragment-order tiled ----------------
template <int K>
__global__ __launch_bounds__(256) void k_presplit(const float* __restrict__ Y,
                                                  ushort* __restrict__ Xh, ushort* __restrict__ Xl) {
  const int CP = K / 4;
  int idx = blockIdx.x * 256 + threadIdx.x;
  int row = idx / CP;
  int c4 = (idx % CP) * 4;
  if (row >= NN) return;
  float4 v = *reinterpret_cast<const float4*>(Y + (size_t)row * K + c4);
  ushort h0 = f2bf(v.x), h1 = f2bf(v.y), h2 = f2bf(v.z), h3 = f2bf(v.w);
  ushort l0 = f2bf(v.x - bf2f(h0)), l1 = f2bf(v.y - bf2f(h1));
  ushort l2 = f2bf(v.z - bf2f(h2)), l3 = f2bf(v.w - bf2f(h3));
  int b = row >> 7, g = (row & 127) >> 4, frow = row & 15;
  int ks = c4 >> 5, qq = (c4 & 31) >> 3, j = c4 & 7;
  size_t base = ((size_t)ks * NB + b) * 4096 + (((g * 4 + qq) * 16) + frow) * 8 + j;
  *reinterpret_cast<uint2*>(Xh + base) =
      make_uint2((uint)h0 | ((uint)h1 << 16), (uint)h2 | ((uint)h3 << 16));
  *reinterpret_cast<uint2*>(Xl + base) =
      make_uint2((uint)l0 | ((uint)l1 << 16), (uint)l2 | ((uint)l3 << 16));
}

// ---------------- MFMA GEMM (pre-split A and B, global_load_lds staging) ----------------
// Flattened grid with XCD-coherent A-sharing: bids {c, c+8, c+16, c+24} cover the
// 4 mats of one row-block and land on the same XCD (round-robin dispatch) -> A L2 hits.
// Pass policy: mats 0-2 (q,k,v -> bf16 outputs) use 2-pass ah*bh + ah*bl (weight-low
// kept: weight rounding is systematic and does NOT pool away; activation-low dropped:
// random across nodes, pools away and is below the output bf16 rounding anyway).
// mat 3 (s -> f32 skip path) keeps full 3-pass.
template <int K>
__global__ __launch_bounds__(256, 2) void k_gemm(
    const ushort* __restrict__ Xh, const ushort* __restrict__ Xl,
    const ushort* __restrict__ Wth, const ushort* __restrict__ Wtl,
    const float* __restrict__ b0, const float* __restrict__ b1,
    const float* __restrict__ b2, const float* __restrict__ b3,
    ushort* __restrict__ qbf, ushort* __restrict__ kv, float* __restrict__ Yxs) {
  __shared__ __align__(16) ushort Ah[4096];
  __shared__ __align__(16) ushort Al[4096];
  __shared__ __align__(16) ushort Bh[4096];
  __shared__ __align__(16) ushort Bl[4096];
  int bid = blockIdx.x;
  int mat = (bid >> 3) & 3;
  int b = (bid & 7) + ((bid >> 5) << 3);
  if (b >= NB) return;
  bool full = (mat == 3);
  int t = threadIdx.x;
  int lane = t & 63, w = t >> 6;
  int wr = w >> 1, wc = w & 1;
  int frow = lane & 15;
  const ushort* wh = Wth + (size_t)mat * (K * 128);
  const ushort* wl = Wtl + (size_t)mat * (K * 128);
  const float* bb = (mat == 0) ? b0 : (mat == 1) ? b1 : (mat == 2) ? b2 : b3;

  f32x4 acc[4][4];
#pragma unroll
  for (int i = 0; i < 4; ++i)
#pragma unroll
    for (int j = 0; j < 4; ++j)
#pragma unroll
      for (int r = 0; r < 4; ++r) acc[i][j][r] = 0.f;

  int wofs = w * 1024 + lane * 8;
  for (int ks = 0; ks < K / 32; ++ks) {
    size_t abase = ((size_t)ks * NB + b) * 4096;
    const ushort* gAh = Xh + abase + wofs;
    const ushort* gBh = wh + ks * 4096 + wofs;
    const ushort* gBl = wl + ks * 4096 + wofs;
    gload16(gAh, &Ah[w * 1024]);
    gload16(gAh + 512, &Ah[w * 1024 + 512]);
    gload16(gBh, &Bh[w * 1024]);
    gload16(gBh + 512, &Bh[w * 1024 + 512]);
    gload16(gBl, &Bl[w * 1024]);
    gload16(gBl + 512, &Bl[w * 1024 + 512]);
    if (full) {
      const ushort* gAl = Xl + abase + wofs;
      gload16(gAl, &Al[w * 1024]);
      gload16(gAl + 512, &Al[w * 1024 + 512]);
    }
    __syncthreads();
    s16x8 ah[4], bh[4], bl[4];
#pragma unroll
    for (int g = 0; g < 4; ++g) {
      ah[g] = *reinterpret_cast<const s16x8*>(&Ah[(wr * 4 + g) * 512 + lane * 8]);
      bh[g] = *reinterpret_cast<const s16x8*>(&Bh[(wc * 4 + g) * 512 + lane * 8]);
      bl[g] = *reinterpret_cast<const s16x8*>(&Bl[(wc * 4 + g) * 512 + lane * 8]);
    }
    if (full) {
      s16x8 al[4];
#pragma unroll
      for (int g = 0; g < 4; ++g)
        al[g] = *reinterpret_cast<const s16x8*>(&Al[(wr * 4 + g) * 512 + lane * 8]);
#pragma unroll
      for (int rg = 0; rg < 4; ++rg)
#pragma unroll
        for (int cg = 0; cg < 4; ++cg) {
          acc[rg][cg] = __builtin_amdgcn_mfma_f32_16x16x32_bf16(ah[rg], bh[cg], acc[rg][cg], 0, 0, 0);
          acc[rg][cg] = __builtin_amdgcn_mfma_f32_16x16x32_bf16(al[rg], bh[cg], acc[rg][cg], 0, 0, 0);
          acc[rg][cg] = __builtin_amdgcn_mfma_f32_16x16x32_bf16(ah[rg], bl[cg], acc[rg][cg], 0, 0, 0);
        }
    } else {
#pragma unroll
      for (int rg = 0; rg < 4; ++rg)
#pragma unroll
        for (int cg = 0; cg < 4; ++cg) {
          acc[rg][cg] = __builtin_amdgcn_mfma_f32_16x16x32_bf16(ah[rg], bh[cg], acc[rg][cg], 0, 0, 0);
          acc[rg][cg] = __builtin_amdgcn_mfma_f32_16x16x32_bf16(ah[rg], bl[cg], acc[rg][cg], 0, 0, 0);
        }
    }
    __syncthreads();
  }
  int r0 = b * 128;
  int qq = (lane >> 4) << 2;
#pragma unroll
  for (int rg = 0; rg < 4; ++rg) {
#pragma unroll
    for (int cg = 0; cg < 4; ++cg) {
      int colg = wc * 64 + cg * 16 + frow;
      float bv = bb[colg];
#pragma unroll
      for (int r = 0; r < 4; ++r) {
        int row = r0 + wr * 64 + rg * 16 + qq + r;
        if (row >= NN) continue;
        float val = acc[rg][cg][r] + bv;
        if (mat == 0)      qbf[(size_t)row * FHH + colg] = f2bf(val * QSCALE);
        else if (mat == 3) Yxs[(size_t)row * FHH + colg] = val;
        else {
          int pos = (colg >> 1) * 4 + ((mat == 2) ? 2 : 0) + (colg & 1);
          kv[(size_t)row * 256 + pos] = f2bf(val);
        }
      }
    }
  }
}

// ---------------- node-centric softmax aggregate (no-max, exp2, bf16 q, byte-offset col) ----------------
// 64 lanes per node, 2 features/lane; 4 nodes per 256-thread block. No cross-wave barriers.
__global__ __launch_bounds__(256) void k_agg(const uint* __restrict__ qb,
                                             const ushort* __restrict__ kv,
                                             const float* __restrict__ xs,
                                             const int* __restrict__ row_ptr,
                                             const uint* __restrict__ colb,
                                             float* __restrict__ y) {
  int n = blockIdx.x * 4 + (threadIdx.x >> 6);
  int t = threadIdx.x & 63;
  uint qp = qb[(n << 6) + t];
  float qx = bfl(qp), qy = bfh(qp);     // q pre-scaled by 0.25*log2e
  const char* kvb = (const char*)kv;
  uint tof = (uint)t * 8u;
  int e0 = row_ptr[n], e1 = row_ptr[n + 1];
  float sum = 0.f, a0 = 0.f, a1 = 0.f;
  int i = e0;
  for (; i + 4 <= e1; i += 4) {
    uint o0 = colb[i] + tof, o1 = colb[i + 1] + tof;
    uint o2 = colb[i + 2] + tof, o3 = colb[i + 3] + tof;
    uint2 d0 = *(const uint2*)(kvb + o0);
    uint2 d1 = *(const uint2*)(kvb + o1);
    uint2 d2 = *(const uint2*)(kvb + o2);
    uint2 d3 = *(const uint2*)(kvb + o3);
    float p0 = fmaf(qx, bfl(d0.x), qy * bfh(d0.x));
    float p1 = fmaf(qx, bfl(d1.x), qy * bfh(d1.x));
    float p2 = fmaf(qx, bfl(d2.x), qy * bfh(d2.x));
    float p3 = fmaf(qx, bfl(d3.x), qy * bfh(d3.x));
    p0 += __shfl_xor(p0, 1, 8); p1 += __shfl_xor(p1, 1, 8);
    p2 += __shfl_xor(p2, 1, 8); p3 += __shfl_xor(p3, 1, 8);
    p0 += __shfl_xor(p0, 2, 8); p1 += __shfl_xor(p1, 2, 8);
    p2 += __shfl_xor(p2, 2, 8); p3 += __shfl_xor(p3, 2, 8);
    p0 += __shfl_xor(p0, 4, 8); p1 += __shfl_xor(p1, 4, 8);
    p2 += __shfl_xor(p2, 4, 8); p3 += __shfl_xor(p3, 4, 8);
    float w0 = exp2f(fminf(p0, 110.f));
    float w1 = exp2f(fminf(p1, 110.f));
    float w2 = exp2f(fminf(p2, 110.f));
    float w3 = exp2f(fminf(p3, 110.f));
    sum += (w0 + w1) + (w2 + w3);
    a0 = fmaf(w0, bfl(d0.y), fmaf(w1, bfl(d1.y), fmaf(w2, bfl(d2.y), fmaf(w3, bfl(d3.y), a0))));
    a1 = fmaf(w0, bfh(d0.y), fmaf(w1, bfh(d1.y), fmaf(w2, bfh(d2.y), fmaf(w3, bfh(d3.y), a1))));
  }
  for (; i < e1; ++i) {
    uint o0 = colb[i] + tof;
    uint2 d0 = *(const uint2*)(kvb + o0);
    float p0 = fmaf(qx, bfl(d0.x), qy * bfh(d0.x));
    p0 += __shfl_xor(p0, 1, 8);
    p0 += __shfl_xor(p0, 2, 8);
    p0 += __shfl_xor(p0, 4, 8);
    float w0 = exp2f(fminf(p0, 110.f));
    sum += w0;
    a0 = fmaf(w0, bfl(d0.y), a0);
    a1 = fmaf(w0, bfh(d0.y), a1);
  }
  float inv = 1.f / fmaxf(sum, 1e-16f);
  float2 xv = *reinterpret_cast<const float2*>(xs + ((size_t)n << 7) + 2 * t);
  float2 ov;
  ov.x = fmaf(a0, inv, xv.x);
  ov.y = fmaf(a1, inv, xv.y);
  *reinterpret_cast<float2*>(y + ((size_t)n << 7) + 2 * t) = ov;
}

// ---------------- BN statistics ----------------
__global__ __launch_bounds__(256) void k_bnstats(const float* __restrict__ y,
                                                 float* __restrict__ sums,
                                                 float* __restrict__ sumsq) {
  __shared__ float s1[256], s2[256];
  int f = threadIdx.x & 127;
  int half = threadIdx.x >> 7;
  float a = 0.f, b = 0.f;
  for (int r = blockIdx.x * 2 + half; r < NN; r += 512) {
    float val = y[(size_t)r * FHH + f];
    a += val;
    b += val * val;
  }
  s1[threadIdx.x] = a;
  s2[threadIdx.x] = b;
  __syncthreads();
  if (half == 0) {
    a += s1[threadIdx.x + 128];
    b += s2[threadIdx.x + 128];
    atomicAdd(&sums[f], a);
    atomicAdd(&sumsq[f], b);
  }
}

// ---------------- fused post: BN+ReLU once -> (pool atomic means) + (split-bf16 fragment write) ----------
// grid 6250, block 256: 8 rows x 128 cols per block
template <int WRITE_X>
__global__ __launch_bounds__(256) void k_post(const float* __restrict__ y,
                                              const float* __restrict__ sums,
                                              const float* __restrict__ sumsq,
                                              const float* __restrict__ gvec,
                                              const float* __restrict__ bvec_,
                                              const int* __restrict__ bv,
                                              const int* __restrict__ gstart,
                                              float* __restrict__ out, int layer,
                                              ushort* __restrict__ Xh, ushort* __restrict__ Xl) {
  __shared__ float acts[8][128];
  __shared__ int sg[8];
  __shared__ float ssc[128], ssh[128];
  int b = blockIdx.x, t = threadIdx.x;
  if (t < 128) {
    const float invn = 1.f / (float)NN;
    float mu = sums[t] * invn;
    float var = sumsq[t] * invn - mu * mu;
    float sc = gvec[t] * rsqrtf(var + 1e-5f);
    ssc[t] = sc;
    ssh[t] = bvec_[t] - mu * sc;
  }
  if (t < 8) sg[t] = (b * 8 + t < NN) ? bv[b * 8 + t] : -1;
  __syncthreads();
  int row = b * 8 + (t >> 5);
  int c4 = (t & 31) * 4;
  bool ok = row < NN;
  float4 a = make_float4(0.f, 0.f, 0.f, 0.f);
  if (ok) {
    float4 v = *reinterpret_cast<const float4*>(y + (size_t)row * FHH + c4);
    a.x = fmaxf(fmaf(v.x, ssc[c4 + 0], ssh[c4 + 0]), 0.f);
    a.y = fmaxf(fmaf(v.y, ssc[c4 + 1], ssh[c4 + 1]), 0.f);
    a.z = fmaxf(fmaf(v.z, ssc[c4 + 2], ssh[c4 + 2]), 0.f);
    a.w = fmaxf(fmaf(v.w, ssc[c4 + 3], ssh[c4 + 3]), 0.f);
  }
  *reinterpret_cast<float4*>(&acts[t >> 5][c4]) = a;
  if (WRITE_X && ok) {
    ushort h0 = f2bf(a.x), h1 = f2bf(a.y), h2 = f2bf(a.z), h3 = f2bf(a.w);
    ushort l0 = f2bf(a.x - bf2f(h0)), l1 = f2bf(a.y - bf2f(h1));
    ushort l2 = f2bf(a.z - bf2f(h2)), l3 = f2bf(a.w - bf2f(h3));
    int bb = row >> 7, g = (row & 127) >> 4, frow = row & 15;
    int ks = c4 >> 5, qq = (c4 & 31) >> 3, j = c4 & 7;
    size_t base = ((size_t)ks * NB + bb) * 4096 + (((g * 4 + qq) * 16) + frow) * 8 + j;
    *reinterpret_cast<uint2*>(Xh + base) =
        make_uint2((uint)h0 | ((uint)h1 << 16), (uint)h2 | ((uint)h3 << 16));
    *reinterpret_cast<uint2*>(Xl + base) =
        make_uint2((uint)l0 | ((uint)l1 << 16), (uint)l2 | ((uint)l3 << 16));
  }
  __syncthreads();
  if (t < 128) {
    float racc = 0.f;
    int cg = sg[0];
    for (int r = 0; r < 8; ++r) {
      int g = sg[r];
      if (g != cg) {
        if (cg >= 0) {
          float p = racc / (float)(gstart[cg + 1] - gstart[cg]);
          if (layer < 5) atomicAdd(&out[(size_t)cg * 1024 + layer * FHH + t], p);
          else {
            atomicAdd(&out[(size_t)cg * 1024 + 5 * FHH + t], p);
            atomicAdd(&out[(size_t)cg * 1024 + 6 * FHH + t], p);
            atomicAdd(&out[(size_t)cg * 1024 + 7 * FHH + t], p);
          }
        }
        racc = 0.f;
        cg = g;
      }
      racc += acts[r][t];
    }
    if (cg >= 0) {
      float p = racc / (float)(gstart[cg + 1] - gstart[cg]);
      if (layer < 5) atomicAdd(&out[(size_t)cg * 1024 + layer * FHH + t], p);
      else {
        atomicAdd(&out[(size_t)cg * 1024 + 5 * FHH + t], p);
        atomicAdd(&out[(size_t)cg * 1024 + 6 * FHH + t], p);
        atomicAdd(&out[(size_t)cg * 1024 + 7 * FHH + t], p);
      }
    }
  }
}

extern "C" void kernel_launch(void* const* d_in, const int* in_sizes, int n_in,
                              void* d_out, int out_size, void* d_ws, size_t ws_size,
                              hipStream_t stream) {
  (void)in_sizes; (void)n_in; (void)ws_size;
  const float* x    = (const float*)d_in[0];
  const int*   ei   = (const int*)d_in[1];
  const int*   bvec = (const int*)d_in[2];
  const float* Wq0  = (const float*)d_in[3];
  const float* bq0  = (const float*)d_in[4];
  const float* Wk0  = (const float*)d_in[5];
  const float* bk0  = (const float*)d_in[6];
  const float* Wv0  = (const float*)d_in[7];
  const float* bv0  = (const float*)d_in[8];
  const float* Ws0  = (const float*)d_in[9];
  const float* bs0  = (const float*)d_in[10];
  const float* WqS  = (const float*)d_in[11];
  const float* bqS  = (const float*)d_in[12];
  const float* WkS  = (const float*)d_in[13];
  const float* bkS  = (const float*)d_in[14];
  const float* WvS  = (const float*)d_in[15];
  const float* bvS  = (const float*)d_in[16];
  const float* WsS  = (const float*)d_in[17];
  const float* bsS  = (const float*)d_in[18];
  const float* gamma = (const float*)d_in[19];
  const float* beta  = (const float*)d_in[20];
  float* out = (float*)d_out;

  char* ws = (char*)d_ws;
  size_t off = 0;
  auto alloc = [&](size_t bytes) {
    void* p = ws + off;
    off = (off + bytes + 255) & ~(size_t)255;
    return p;
  };
  ushort* qbf = (ushort*)alloc((size_t)NN * FHH * 2);
  float* xs   = (float*)alloc((size_t)NN * FHH * 4);
  float* y    = (float*)alloc((size_t)NN * FHH * 4);
  ushort* kv  = (ushort*)alloc((size_t)NN * 256 * 2);
  ushort* Xh  = (ushort*)alloc((size_t)4 * NB * 4096 * 2 + 8192);
  ushort* Xl  = (ushort*)alloc((size_t)4 * NB * 4096 * 2 + 8192);
  uint* colb   = (uint*)alloc((size_t)NE * 4);
  int* row_ptr = (int*)alloc((size_t)(NN + 1) * 4);
  int* cursor  = (int*)alloc((size_t)NN * 4);
  int* deg     = (int*)alloc((size_t)NN * 4);
  int* part    = (int*)alloc((size_t)NCH * 4);
  int* gstart  = (int*)alloc((size_t)(NG + 1) * 4);
  float* bstat = (float*)alloc((size_t)NL * 2 * FHH * 4);   // [layer][{sum,sumsq}][128]
  ushort* wsh = (ushort*)alloc((size_t)360448 * 2);
  ushort* wsl = (ushort*)alloc((size_t)360448 * 2);

  const int* srcv = ei;
  const int* dstv = ei + NE;

  hipMemsetAsync(out, 0, (size_t)out_size * 4, stream);
  hipMemsetAsync(deg, 0, (size_t)NN * 4, stream);
  hipMemsetAsync(bstat, 0, (size_t)NL * 2 * FHH * 4, stream);
  k_gstart<<<5, 64, 0, stream>>>(bvec, gstart);
  k_deg<<<(NE + 255) / 256, 256, 0, stream>>>(dstv, deg);
  k_scanA<<<NCH, 256, 0, stream>>>(deg, part);
  k_scanB<<<1, 64, 0, stream>>>(part, row_ptr);
  k_scanC<<<NCH, 1024, 0, stream>>>(deg, part, row_ptr, cursor);
  k_scatter<<<(NE + 255) / 256, 256, 0, stream>>>(srcv, dstv, cursor, colb);
  k_wconv0<<<128, 256, 0, stream>>>(Wq0, Wk0, Wv0, Ws0, wsh, wsl);
  k_wconvS<<<1280, 256, 0, stream>>>(WqS, WkS, WvS, WsS, wsh, wsl);
  k_presplit<64><<<(NN * 16 + 255) / 256, 256, 0, stream>>>(x, Xh, Xl);

  const int GEMM_GRID = 49 * 32;   // ceil(NB/8)*32 : 4 mats x NB blocks, XCD-swizzled
  for (int l = 0; l < NL; ++l) {
    const ushort* WthL = wsh + ((l == 0) ? 0 : (size_t)32768 + (size_t)(l - 1) * 65536);
    const ushort* WtlL = wsl + ((l == 0) ? 0 : (size_t)32768 + (size_t)(l - 1) * 65536);
    const float *bq_, *bk_, *bv_, *bs_;
    if (l == 0) { bq_ = bq0; bk_ = bk0; bv_ = bv0; bs_ = bs0; }
    else {
      size_t bo = (size_t)(l - 1) * FHH;
      bq_ = bqS + bo; bk_ = bkS + bo; bv_ = bvS + bo; bs_ = bsS + bo;
    }
    if (l == 0)
      k_gemm<64><<<GEMM_GRID, 256, 0, stream>>>(Xh, Xl, WthL, WtlL, bq_, bk_, bv_, bs_, qbf, kv, xs);
    else
      k_gemm<128><<<GEMM_GRID, 256, 0, stream>>>(Xh, Xl, WthL, WtlL, bq_, bk_, bv_, bs_, qbf, kv, xs);
    k_agg<<<NN / 4, 256, 0, stream>>>((const uint*)qbf, kv, xs, row_ptr, colb, y);
    float* lsum = bstat + (size_t)l * 2 * FHH;
    float* lsqs = lsum + FHH;
    k_bnstats<<<256, 256, 0, stream>>>(y, lsum, lsqs);
    if (l + 1 < NL)
      k_post<1><<<6250, 256, 0, stream>>>(y, lsum, lsqs, gamma + (size_t)l * FHH,
                                          beta + (size_t)l * FHH, bvec, gstart, out, l, Xh, Xl);
    else
      k_post<0><<<6250, 256, 0, stream>>>(y, lsum, lsqs, gamma + (size_t)l * FHH,
                                          beta + (size_t)l * FHH, bvec, gstart, out, l, Xh, Xl);
  }
}

// Round 9
// 950.752 us; speedup vs baseline: 1.0977x; 1.0977x over previous
//
#include <hip/hip_runtime.h>
#include <hip/hip_bf16.h>
#include <math.h>

#define NN 50000
#define NE 800000
#define NG 256
#define FHH 128
#define NL 6
#define NCH 49    // ceil(50000/1024)
#define NB 391    // ceil(50000/128) row-blocks

typedef __attribute__((ext_vector_type(8))) short s16x8;
typedef __attribute__((ext_vector_type(4))) float f32x4;

#define QSCALE 0.36067376022224085f   // 0.25 * log2(e)

__device__ __forceinline__ ushort f2bf(float x) {
  uint u = __float_as_uint(x);
  u += 0x7fffu + ((u >> 16) & 1u);
  return (ushort)(u >> 16);
}
__device__ __forceinline__ float bf2f(ushort h) {
  return __uint_as_float(((uint)h) << 16);
}
__device__ __forceinline__ float bfl(uint u) { return __uint_as_float(u << 16); }
__device__ __forceinline__ float bfh(uint u) { return __uint_as_float(u & 0xffff0000u); }
__device__ __forceinline__ uint packbf(float a, float b) {
  return (uint)f2bf(a) | ((uint)f2bf(b) << 16);
}

__device__ __forceinline__ void gload16(const ushort* g, ushort* l) {
  __builtin_amdgcn_global_load_lds(
      (const __attribute__((address_space(1))) uint*)(const void*)g,
      (__attribute__((address_space(3))) uint*)(void*)l, 16, 0, 0);
}

// ---------------- graph-boundary search (batch_vec sorted) ----------------
__global__ void k_gstart(const int* __restrict__ bv, int* __restrict__ gstart) {
  int g = blockIdx.x * blockDim.x + threadIdx.x;
  if (g > NG) return;
  int lo = 0, hi = NN;
  while (lo < hi) { int mid = (lo + hi) >> 1; if (bv[mid] < g) lo = mid + 1; else hi = mid; }
  gstart[g] = lo;
}

// ---------------- CSR build (by dst) ----------------
__global__ void k_deg(const int* __restrict__ dstv, int* __restrict__ deg) {
  int e = blockIdx.x * blockDim.x + threadIdx.x;
  if (e < NE) atomicAdd(&deg[dstv[e]], 1);
}

__global__ __launch_bounds__(256) void k_scanA(const int* __restrict__ deg, int* __restrict__ part) {
  int b = blockIdx.x, t = threadIdx.x;
  int s = 0;
  for (int j = t; j < 1024; j += 256) { int i = b * 1024 + j; if (i < NN) s += deg[i]; }
  __shared__ int sh[4];
  for (int o = 32; o; o >>= 1) s += __shfl_down(s, o, 64);
  if ((t & 63) == 0) sh[t >> 6] = s;
  __syncthreads();
  if (t == 0) part[b] = sh[0] + sh[1] + sh[2] + sh[3];
}

__global__ void k_scanB(int* __restrict__ part, int* __restrict__ row_ptr) {
  if (threadIdx.x == 0 && blockIdx.x == 0) {
    int run = 0;
    for (int i = 0; i < NCH; ++i) { int v = part[i]; part[i] = run; run += v; }
    row_ptr[NN] = run;
  }
}

__global__ __launch_bounds__(1024) void k_scanC(const int* __restrict__ deg, const int* __restrict__ part,
                                                int* __restrict__ row_ptr, int* __restrict__ cursor) {
  __shared__ int buf[1024];
  int b = blockIdx.x, t = threadIdx.x;
  int i = b * 1024 + t;
  int v = (i < NN) ? deg[i] : 0;
  buf[t] = v;
  __syncthreads();
  for (int off = 1; off < 1024; off <<= 1) {
    int add = (t >= off) ? buf[t - off] : 0;
    __syncthreads();
    buf[t] += add;
    __syncthreads();
  }
  if (i < NN) { int ex = part[b] + buf[t] - v; row_ptr[i] = ex; cursor[i] = ex; }
}

// col stores BYTE offsets of kv rows (src * 512)
__global__ void k_scatter(const int* __restrict__ srcv, const int* __restrict__ dstv,
                          int* __restrict__ cursor, uint* __restrict__ colb) {
  int e = blockIdx.x * blockDim.x + threadIdx.x;
  if (e < NE) {
    int d = dstv[e];
    int pos = atomicAdd(&cursor[d], 1);
    colb[pos] = ((uint)srcv[e]) << 9;
  }
}

// ---------------- weight preconvert: fragment-order tiles ----------------
__device__ __forceinline__ size_t wtile_idx(int k, int c) {
  return (size_t)(k >> 5) * 4096 + ((((c >> 4) * 4 + ((k & 31) >> 3)) * 16 + (c & 15)) * 8 + (k & 7));
}

__global__ __launch_bounds__(256) void k_wconv0(const float* __restrict__ W0, const float* __restrict__ W1,
                                                const float* __restrict__ W2, const float* __restrict__ W3,
                                                ushort* __restrict__ wh, ushort* __restrict__ wl) {
  int id = blockIdx.x * 256 + threadIdx.x;           // 4*64*128 = 32768
  if (id >= 4 * 64 * 128) return;
  int mat = id >> 13, rem = id & 8191;
  int k = rem >> 7, c = rem & 127;
  const float* W = (mat == 0) ? W0 : (mat == 1) ? W1 : (mat == 2) ? W2 : W3;
  float v = W[k * 128 + c];
  ushort h = f2bf(v);
  ushort lo = f2bf(v - bf2f(h));
  size_t dst = (size_t)mat * 8192 + wtile_idx(k, c);
  wh[dst] = h; wl[dst] = lo;
}

__global__ __launch_bounds__(256) void k_wconvS(const float* __restrict__ Wq, const float* __restrict__ Wk,
                                                const float* __restrict__ Wv, const float* __restrict__ Ws,
                                                ushort* __restrict__ wh, ushort* __restrict__ wl) {
  int id = blockIdx.x * 256 + threadIdx.x;           // 5*4*128*128 = 327680
  if (id >= 5 * 4 * 16384) return;
  int lay = id / 65536, rem = id % 65536;
  int mat = rem >> 14, rem2 = rem & 16383;
  int k = rem2 >> 7, c = rem2 & 127;
  const float* W = (mat == 0) ? Wq : (mat == 1) ? Wk : (mat == 2) ? Wv : Ws;
  float v = W[(size_t)lay * 16384 + k * 128 + c];
  ushort h = f2bf(v);
  ushort lo = f2bf(v - bf2f(h));
  size_t dst = 32768 + ((size_t)lay * 4 + mat) * 16384 + wtile_idx(k, c);
  wh[dst] = h; wl[dst] = lo;
}

// ---------------- presplit (layer-0 input only): split-bf16, fragment-order tiled ----------------
template <int K>
__global__ __launch_bounds__(256) void k_presplit(const float* __restrict__ Y,
                                                  ushort* __restrict__ Xh, ushort* __restrict__ Xl) {
  const int CP = K / 4;
  int idx = blockIdx.x * 256 + threadIdx.x;
  int row = idx / CP;
  int c4 = (idx % CP) * 4;
  if (row >= NN) return;
  float4 v = *reinterpret_cast<const float4*>(Y + (size_t)row * K + c4);
  ushort h0 = f2bf(v.x), h1 = f2bf(v.y), h2 = f2bf(v.z), h3 = f2bf(v.w);
  ushort l0 = f2bf(v.x - bf2f(h0)), l1 = f2bf(v.y - bf2f(h1));
  ushort l2 = f2bf(v.z - bf2f(h2)), l3 = f2bf(v.w - bf2f(h3));
  int b = row >> 7, g = (row & 127) >> 4, frow = row & 15;
  int ks = c4 >> 5, qq = (c4 & 31) >> 3, j = c4 & 7;
  size_t base = ((size_t)ks * NB + b) * 4096 + (((g * 4 + qq) * 16) + frow) * 8 + j;
  *reinterpret_cast<uint2*>(Xh + base) =
      make_uint2((uint)h0 | ((uint)h1 << 16), (uint)h2 | ((uint)h3 << 16));
  *reinterpret_cast<uint2*>(Xl + base) =
      make_uint2((uint)l0 | ((uint)l1 << 16), (uint)l2 | ((uint)l3 << 16));
}

// ---------------- MFMA GEMM (pre-split A and B, global_load_lds staging) ----------------
// Flattened grid with XCD-coherent A-sharing: bids {c, c+8, c+16, c+24} cover the
// 4 mats of one row-block and land on the same XCD (round-robin dispatch) -> A L2 hits.
// Uniform 3-pass split ah*bh + al*bh + ah*bl (R7-proven).
template <int K>
__global__ __launch_bounds__(256, 2) void k_gemm(
    const ushort* __restrict__ Xh, const ushort* __restrict__ Xl,
    const ushort* __restrict__ Wth, const ushort* __restrict__ Wtl,
    const float* __restrict__ b0, const float* __restrict__ b1,
    const float* __restrict__ b2, const float* __restrict__ b3,
    ushort* __restrict__ qbf, ushort* __restrict__ kv, float* __restrict__ Yxs) {
  __shared__ __align__(16) ushort Ah[4096];
  __shared__ __align__(16) ushort Al[4096];
  __shared__ __align__(16) ushort Bh[4096];
  __shared__ __align__(16) ushort Bl[4096];
  int bid = blockIdx.x;
  int mat = (bid >> 3) & 3;
  int b = (bid & 7) + ((bid >> 5) << 3);
  if (b >= NB) return;
  int t = threadIdx.x;
  int lane = t & 63, w = t >> 6;
  int wr = w >> 1, wc = w & 1;
  int frow = lane & 15;
  const ushort* wh = Wth + (size_t)mat * (K * 128);
  const ushort* wl = Wtl + (size_t)mat * (K * 128);
  const float* bb = (mat == 0) ? b0 : (mat == 1) ? b1 : (mat == 2) ? b2 : b3;

  f32x4 acc[4][4];
#pragma unroll
  for (int i = 0; i < 4; ++i)
#pragma unroll
    for (int j = 0; j < 4; ++j)
#pragma unroll
      for (int r = 0; r < 4; ++r) acc[i][j][r] = 0.f;

  int wofs = w * 1024 + lane * 8;
  for (int ks = 0; ks < K / 32; ++ks) {
    size_t abase = ((size_t)ks * NB + b) * 4096;
    const ushort* gAh = Xh + abase + wofs;
    const ushort* gAl = Xl + abase + wofs;
    const ushort* gBh = wh + ks * 4096 + wofs;
    const ushort* gBl = wl + ks * 4096 + wofs;
    gload16(gAh, &Ah[w * 1024]);
    gload16(gAh + 512, &Ah[w * 1024 + 512]);
    gload16(gAl, &Al[w * 1024]);
    gload16(gAl + 512, &Al[w * 1024 + 512]);
    gload16(gBh, &Bh[w * 1024]);
    gload16(gBh + 512, &Bh[w * 1024 + 512]);
    gload16(gBl, &Bl[w * 1024]);
    gload16(gBl + 512, &Bl[w * 1024 + 512]);
    __syncthreads();
    s16x8 ah[4], al[4], bh[4], bl[4];
#pragma unroll
    for (int g = 0; g < 4; ++g) {
      ah[g] = *reinterpret_cast<const s16x8*>(&Ah[(wr * 4 + g) * 512 + lane * 8]);
      al[g] = *reinterpret_cast<const s16x8*>(&Al[(wr * 4 + g) * 512 + lane * 8]);
      bh[g] = *reinterpret_cast<const s16x8*>(&Bh[(wc * 4 + g) * 512 + lane * 8]);
      bl[g] = *reinterpret_cast<const s16x8*>(&Bl[(wc * 4 + g) * 512 + lane * 8]);
    }
#pragma unroll
    for (int rg = 0; rg < 4; ++rg)
#pragma unroll
      for (int cg = 0; cg < 4; ++cg) {
        acc[rg][cg] = __builtin_amdgcn_mfma_f32_16x16x32_bf16(ah[rg], bh[cg], acc[rg][cg], 0, 0, 0);
        acc[rg][cg] = __builtin_amdgcn_mfma_f32_16x16x32_bf16(al[rg], bh[cg], acc[rg][cg], 0, 0, 0);
        acc[rg][cg] = __builtin_amdgcn_mfma_f32_16x16x32_bf16(ah[rg], bl[cg], acc[rg][cg], 0, 0, 0);
      }
    __syncthreads();
  }
  int r0 = b * 128;
  int qq = (lane >> 4) << 2;
#pragma unroll
  for (int rg = 0; rg < 4; ++rg) {
#pragma unroll
    for (int cg = 0; cg < 4; ++cg) {
      int colg = wc * 64 + cg * 16 + frow;
      float bv = bb[colg];
#pragma unroll
      for (int r = 0; r < 4; ++r) {
        int row = r0 + wr * 64 + rg * 16 + qq + r;
        if (row >= NN) continue;
        float val = acc[rg][cg][r] + bv;
        if (mat == 0)      qbf[(size_t)row * FHH + colg] = f2bf(val * QSCALE);
        else if (mat == 3) Yxs[(size_t)row * FHH + colg] = val;
        else {
          int pos = (colg >> 1) * 4 + ((mat == 2) ? 2 : 0) + (colg & 1);
          kv[(size_t)row * 256 + pos] = f2bf(val);
        }
      }
    }
  }
}

// ---------------- node-centric softmax aggregate (no-max, exp2, bf16 q, byte-offset col) ----------------
// 64 lanes per node, 2 features/lane; 4 nodes per 256-thread block. No cross-wave barriers.
// y written as packed bf16x2 (uint per 2 features).
__global__ __launch_bounds__(256) void k_agg(const uint* __restrict__ qb,
                                             const ushort* __restrict__ kv,
                                             const float* __restrict__ xs,
                                             const int* __restrict__ row_ptr,
                                             const uint* __restrict__ colb,
                                             uint* __restrict__ yb) {
  int n = blockIdx.x * 4 + (threadIdx.x >> 6);
  int t = threadIdx.x & 63;
  uint qp = qb[(n << 6) + t];
  float qx = bfl(qp), qy = bfh(qp);     // q pre-scaled by 0.25*log2e
  const char* kvb = (const char*)kv;
  uint tof = (uint)t * 8u;
  int e0 = row_ptr[n], e1 = row_ptr[n + 1];
  float sum = 0.f, a0 = 0.f, a1 = 0.f;
  int i = e0;
  for (; i + 4 <= e1; i += 4) {
    uint o0 = colb[i] + tof, o1 = colb[i + 1] + tof;
    uint o2 = colb[i + 2] + tof, o3 = colb[i + 3] + tof;
    uint2 d0 = *(const uint2*)(kvb + o0);
    uint2 d1 = *(const uint2*)(kvb + o1);
    uint2 d2 = *(const uint2*)(kvb + o2);
    uint2 d3 = *(const uint2*)(kvb + o3);
    float p0 = fmaf(qx, bfl(d0.x), qy * bfh(d0.x));
    float p1 = fmaf(qx, bfl(d1.x), qy * bfh(d1.x));
    float p2 = fmaf(qx, bfl(d2.x), qy * bfh(d2.x));
    float p3 = fmaf(qx, bfl(d3.x), qy * bfh(d3.x));
    p0 += __shfl_xor(p0, 1, 8); p1 += __shfl_xor(p1, 1, 8);
    p2 += __shfl_xor(p2, 1, 8); p3 += __shfl_xor(p3, 1, 8);
    p0 += __shfl_xor(p0, 2, 8); p1 += __shfl_xor(p1, 2, 8);
    p2 += __shfl_xor(p2, 2, 8); p3 += __shfl_xor(p3, 2, 8);
    p0 += __shfl_xor(p0, 4, 8); p1 += __shfl_xor(p1, 4, 8);
    p2 += __shfl_xor(p2, 4, 8); p3 += __shfl_xor(p3, 4, 8);
    float w0 = exp2f(fminf(p0, 110.f));
    float w1 = exp2f(fminf(p1, 110.f));
    float w2 = exp2f(fminf(p2, 110.f));
    float w3 = exp2f(fminf(p3, 110.f));
    sum += (w0 + w1) + (w2 + w3);
    a0 = fmaf(w0, bfl(d0.y), fmaf(w1, bfl(d1.y), fmaf(w2, bfl(d2.y), fmaf(w3, bfl(d3.y), a0))));
    a1 = fmaf(w0, bfh(d0.y), fmaf(w1, bfh(d1.y), fmaf(w2, bfh(d2.y), fmaf(w3, bfh(d3.y), a1))));
  }
  for (; i < e1; ++i) {
    uint o0 = colb[i] + tof;
    uint2 d0 = *(const uint2*)(kvb + o0);
    float p0 = fmaf(qx, bfl(d0.x), qy * bfh(d0.x));
    p0 += __shfl_xor(p0, 1, 8);
    p0 += __shfl_xor(p0, 2, 8);
    p0 += __shfl_xor(p0, 4, 8);
    float w0 = exp2f(fminf(p0, 110.f));
    sum += w0;
    a0 = fmaf(w0, bfl(d0.y), a0);
    a1 = fmaf(w0, bfh(d0.y), a1);
  }
  float inv = 1.f / fmaxf(sum, 1e-16f);
  float2 xv = *reinterpret_cast<const float2*>(xs + ((size_t)n << 7) + 2 * t);
  float ox = fmaf(a0, inv, xv.x);
  float oy = fmaf(a1, inv, xv.y);
  yb[(n << 6) + t] = packbf(ox, oy);
}

// ---------------- BN statistics (packed bf16 y) ----------------
// grid 256, block 256: thread = (uint index u = t&63, row-group = t>>6)
__global__ __launch_bounds__(256) void k_bnstats(const uint* __restrict__ yb,
                                                 float* __restrict__ stats) {
  __shared__ float2 s1[256], s2[256];
  int u = threadIdx.x & 63;
  int grp = threadIdx.x >> 6;
  float2 a = make_float2(0.f, 0.f), b = make_float2(0.f, 0.f);
  for (int r = blockIdx.x * 4 + grp; r < NN; r += 1024) {
    uint d = yb[(size_t)r * 64 + u];
    float x = bfl(d), yv = bfh(d);
    a.x += x; a.y += yv;
    b.x = fmaf(x, x, b.x); b.y = fmaf(yv, yv, b.y);
  }
  s1[threadIdx.x] = a;
  s2[threadIdx.x] = b;
  __syncthreads();
  if (grp == 0) {
#pragma unroll
    for (int g = 1; g < 4; ++g) {
      a.x += s1[u + 64 * g].x; a.y += s1[u + 64 * g].y;
      b.x += s2[u + 64 * g].x; b.y += s2[u + 64 * g].y;
    }
    atomicAdd(&stats[2 * u], a.x);
    atomicAdd(&stats[2 * u + 1], a.y);
    atomicAdd(&stats[128 + 2 * u], b.x);
    atomicAdd(&stats[128 + 2 * u + 1], b.y);
  }
}

// ---------------- fused post: BN+ReLU once -> (pool atomic means) + (split-bf16 fragment write) ----------
// grid 6250, block 256: 8 rows x 128 cols per block; y is packed bf16.
template <int WRITE_X>
__global__ __launch_bounds__(256) void k_post(const uint* __restrict__ yb,
                                              const float* __restrict__ st,
                                              const float* __restrict__ gvec,
                                              const float* __restrict__ bvec_,
                                              const int* __restrict__ bv,
                                              const int* __restrict__ gstart,
                                              float* __restrict__ out, int layer,
                                              ushort* __restrict__ Xh, ushort* __restrict__ Xl) {
  __shared__ float acts[8][128];
  __shared__ int sg[8];
  __shared__ float ssc[128], ssh[128];
  int b = blockIdx.x, t = threadIdx.x;
  if (t < 128) {
    const float invn = 1.f / (float)NN;
    float mu = st[t] * invn;
    float var = st[128 + t] * invn - mu * mu;
    float sc = gvec[t] * rsqrtf(var + 1e-5f);
    ssc[t] = sc;
    ssh[t] = bvec_[t] - mu * sc;
  }
  if (t < 8) sg[t] = (b * 8 + t < NN) ? bv[b * 8 + t] : -1;
  __syncthreads();
  int row = b * 8 + (t >> 5);
  int c4 = (t & 31) * 4;
  bool ok = row < NN;
  float4 a = make_float4(0.f, 0.f, 0.f, 0.f);
  if (ok) {
    uint2 u2 = *reinterpret_cast<const uint2*>(yb + (size_t)row * 64 + (c4 >> 1));
    a.x = fmaxf(fmaf(bfl(u2.x), ssc[c4 + 0], ssh[c4 + 0]), 0.f);
    a.y = fmaxf(fmaf(bfh(u2.x), ssc[c4 + 1], ssh[c4 + 1]), 0.f);
    a.z = fmaxf(fmaf(bfl(u2.y), ssc[c4 + 2], ssh[c4 + 2]), 0.f);
    a.w = fmaxf(fmaf(bfh(u2.y), ssc[c4 + 3], ssh[c4 + 3]), 0.f);
  }
  *reinterpret_cast<float4*>(&acts[t >> 5][c4]) = a;
  if (WRITE_X && ok) {
    ushort h0 = f2bf(a.x), h1 = f2bf(a.y), h2 = f2bf(a.z), h3 = f2bf(a.w);
    ushort l0 = f2bf(a.x - bf2f(h0)), l1 = f2bf(a.y - bf2f(h1));
    ushort l2 = f2bf(a.z - bf2f(h2)), l3 = f2bf(a.w - bf2f(h3));
    int bb = row >> 7, g = (row & 127) >> 4, frow = row & 15;
    int ks = c4 >> 5, qq = (c4 & 31) >> 3, j = c4 & 7;
    size_t base = ((size_t)ks * NB + bb) * 4096 + (((g * 4 + qq) * 16) + frow) * 8 + j;
    *reinterpret_cast<uint2*>(Xh + base) =
        make_uint2((uint)h0 | ((uint)h1 << 16), (uint)h2 | ((uint)h3 << 16));
    *reinterpret_cast<uint2*>(Xl + base) =
        make_uint2((uint)l0 | ((uint)l1 << 16), (uint)l2 | ((uint)l3 << 16));
  }
  __syncthreads();
  if (t < 128) {
    float racc = 0.f;
    int cg = sg[0];
    for (int r = 0; r < 8; ++r) {
      int g = sg[r];
      if (g != cg) {
        if (cg >= 0) {
          float p = racc / (float)(gstart[cg + 1] - gstart[cg]);
          if (layer < 5) atomicAdd(&out[(size_t)cg * 1024 + layer * FHH + t], p);
          else {
            atomicAdd(&out[(size_t)cg * 1024 + 5 * FHH + t], p);
            atomicAdd(&out[(size_t)cg * 1024 + 6 * FHH + t], p);
            atomicAdd(&out[(size_t)cg * 1024 + 7 * FHH + t], p);
          }
        }
        racc = 0.f;
        cg = g;
      }
      racc += acts[r][t];
    }
    if (cg >= 0) {
      float p = racc / (float)(gstart[cg + 1] - gstart[cg]);
      if (layer < 5) atomicAdd(&out[(size_t)cg * 1024 + layer * FHH + t], p);
      else {
        atomicAdd(&out[(size_t)cg * 1024 + 5 * FHH + t], p);
        atomicAdd(&out[(size_t)cg * 1024 + 6 * FHH + t], p);
        atomicAdd(&out[(size_t)cg * 1024 + 7 * FHH + t], p);
      }
    }
  }
}

extern "C" void kernel_launch(void* const* d_in, const int* in_sizes, int n_in,
                              void* d_out, int out_size, void* d_ws, size_t ws_size,
                              hipStream_t stream) {
  (void)in_sizes; (void)n_in; (void)ws_size;
  const float* x    = (const float*)d_in[0];
  const int*   ei   = (const int*)d_in[1];
  const int*   bvec = (const int*)d_in[2];
  const float* Wq0  = (const float*)d_in[3];
  const float* bq0  = (const float*)d_in[4];
  const float* Wk0  = (const float*)d_in[5];
  const float* bk0  = (const float*)d_in[6];
  const float* Wv0  = (const float*)d_in[7];
  const float* bv0  = (const float*)d_in[8];
  const float* Ws0  = (const float*)d_in[9];
  const float* bs0  = (const float*)d_in[10];
  const float* WqS  = (const float*)d_in[11];
  const float* bqS  = (const float*)d_in[12];
  const float* WkS  = (const float*)d_in[13];
  const float* bkS  = (const float*)d_in[14];
  const float* WvS  = (const float*)d_in[15];
  const float* bvS  = (const float*)d_in[16];
  const float* WsS  = (const float*)d_in[17];
  const float* bsS  = (const float*)d_in[18];
  const float* gamma = (const float*)d_in[19];
  const float* beta  = (const float*)d_in[20];
  float* out = (float*)d_out;

  char* ws = (char*)d_ws;
  size_t off = 0;
  auto alloc = [&](size_t bytes) {
    void* p = ws + off;
    off = (off + bytes + 255) & ~(size_t)255;
    return p;
  };
  ushort* qbf = (ushort*)alloc((size_t)NN * FHH * 2);
  float* xs   = (float*)alloc((size_t)NN * FHH * 4);
  uint* yb    = (uint*)alloc((size_t)NN * 64 * 4);
  ushort* kv  = (ushort*)alloc((size_t)NN * 256 * 2);
  ushort* Xh  = (ushort*)alloc((size_t)4 * NB * 4096 * 2 + 8192);
  ushort* Xl  = (ushort*)alloc((size_t)4 * NB * 4096 * 2 + 8192);
  uint* colb   = (uint*)alloc((size_t)NE * 4);
  int* row_ptr = (int*)alloc((size_t)(NN + 1) * 4);
  int* cursor  = (int*)alloc((size_t)NN * 4);
  int* deg     = (int*)alloc((size_t)NN * 4);
  int* part    = (int*)alloc((size_t)NCH * 4);
  int* gstart  = (int*)alloc((size_t)(NG + 1) * 4);
  float* bstat = (float*)alloc((size_t)NL * 2 * FHH * 4);   // [layer][{sum,sumsq}][128]
  ushort* wsh = (ushort*)alloc((size_t)360448 * 2);
  ushort* wsl = (ushort*)alloc((size_t)360448 * 2);

  const int* srcv = ei;
  const int* dstv = ei + NE;

  hipMemsetAsync(out, 0, (size_t)out_size * 4, stream);
  hipMemsetAsync(deg, 0, (size_t)NN * 4, stream);
  hipMemsetAsync(bstat, 0, (size_t)NL * 2 * FHH * 4, stream);
  k_gstart<<<5, 64, 0, stream>>>(bvec, gstart);
  k_deg<<<(NE + 255) / 256, 256, 0, stream>>>(dstv, deg);
  k_scanA<<<NCH, 256, 0, stream>>>(deg, part);
  k_scanB<<<1, 64, 0, stream>>>(part, row_ptr);
  k_scanC<<<NCH, 1024, 0, stream>>>(deg, part, row_ptr, cursor);
  k_scatter<<<(NE + 255) / 256, 256, 0, stream>>>(srcv, dstv, cursor, colb);
  k_wconv0<<<128, 256, 0, stream>>>(Wq0, Wk0, Wv0, Ws0, wsh, wsl);
  k_wconvS<<<1280, 256, 0, stream>>>(WqS, WkS, WvS, WsS, wsh, wsl);
  k_presplit<64><<<(NN * 16 + 255) / 256, 256, 0, stream>>>(x, Xh, Xl);

  const int GEMM_GRID = 49 * 32;   // ceil(NB/8)*32 : 4 mats x NB blocks, XCD-swizzled
  for (int l = 0; l < NL; ++l) {
    const ushort* WthL = wsh + ((l == 0) ? 0 : (size_t)32768 + (size_t)(l - 1) * 65536);
    const ushort* WtlL = wsl + ((l == 0) ? 0 : (size_t)32768 + (size_t)(l - 1) * 65536);
    const float *bq_, *bk_, *bv_, *bs_;
    if (l == 0) { bq_ = bq0; bk_ = bk0; bv_ = bv0; bs_ = bs0; }
    else {
      size_t bo = (size_t)(l - 1) * FHH;
      bq_ = bqS + bo; bk_ = bkS + bo; bv_ = bvS + bo; bs_ = bsS + bo;
    }
    if (l == 0)
      k_gemm<64><<<GEMM_GRID, 256, 0, stream>>>(Xh, Xl, WthL, WtlL, bq_, bk_, bv_, bs_, qbf, kv, xs);
    else
      k_gemm<128><<<GEMM_GRID, 256, 0, stream>>>(Xh, Xl, WthL, WtlL, bq_, bk_, bv_, bs_, qbf, kv, xs);
    k_agg<<<NN / 4, 256, 0, stream>>>((const uint*)qbf, kv, xs, row_ptr, colb, yb);
    float* lstat = bstat + (size_t)l * 2 * FHH;
    k_bnstats<<<256, 256, 0, stream>>>(yb, lstat);
    if (l + 1 < NL)
      k_post<1><<<6250, 256, 0, stream>>>(yb, lstat, gamma + (size_t)l * FHH,
                                          beta + (size_t)l * FHH, bvec, gstart, out, l, Xh, Xl);
    else
      k_post<0><<<6250, 256, 0, stream>>>(yb, lstat, gamma + (size_t)l * FHH,
                                          beta + (size_t)l * FHH, bvec, gstart, out, l, Xh, Xl);
  }
}

// Round 10
// 941.395 us; speedup vs baseline: 1.1086x; 1.0099x over previous
//
#include <hip/hip_runtime.h>
#include <hip/hip_bf16.h>
#include <math.h>

#define NN 50000
#define NE 800000
#define NG 256
#define FHH 128
#define NL 6
#define NCH 49    // ceil(50000/1024)
#define NB 391    // ceil(50000/128) row-blocks

typedef __attribute__((ext_vector_type(8))) short s16x8;
typedef __attribute__((ext_vector_type(4))) float f32x4;

#define QSCALE 0.36067376022224085f   // 0.25 * log2(e)

#if defined(__has_builtin)
#if __has_builtin(__builtin_amdgcn_fdot2_f32_bf16)
#define HAVE_BFDOT 1
#endif
#endif
#ifndef HAVE_BFDOT
#define HAVE_BFDOT 0
#endif

__device__ __forceinline__ ushort f2bf(float x) {
  uint u = __float_as_uint(x);
  u += 0x7fffu + ((u >> 16) & 1u);
  return (ushort)(u >> 16);
}
__device__ __forceinline__ float bf2f(ushort h) {
  return __uint_as_float(((uint)h) << 16);
}
__device__ __forceinline__ float bfl(uint u) { return __uint_as_float(u << 16); }
__device__ __forceinline__ float bfh(uint u) { return __uint_as_float(u & 0xffff0000u); }
__device__ __forceinline__ uint packbf(float a, float b) {
  return (uint)f2bf(a) | ((uint)f2bf(b) << 16);
}

#if HAVE_BFDOT
typedef __attribute__((ext_vector_type(2))) __bf16 bf16v2;
__device__ __forceinline__ float dot2acc(uint a, uint b, float acc) {
  return __builtin_amdgcn_fdot2_f32_bf16(__builtin_bit_cast(bf16v2, a),
                                         __builtin_bit_cast(bf16v2, b), acc, false);
}
#endif

__device__ __forceinline__ void gload16(const ushort* g, ushort* l) {
  __builtin_amdgcn_global_load_lds(
      (const __attribute__((address_space(1))) uint*)(const void*)g,
      (__attribute__((address_space(3))) uint*)(void*)l, 16, 0, 0);
}

// ---------------- graph-boundary search (batch_vec sorted) ----------------
__global__ void k_gstart(const int* __restrict__ bv, int* __restrict__ gstart) {
  int g = blockIdx.x * blockDim.x + threadIdx.x;
  if (g > NG) return;
  int lo = 0, hi = NN;
  while (lo < hi) { int mid = (lo + hi) >> 1; if (bv[mid] < g) lo = mid + 1; else hi = mid; }
  gstart[g] = lo;
}

// ---------------- CSR build (by dst) ----------------
__global__ void k_deg(const int* __restrict__ dstv, int* __restrict__ deg) {
  int e = blockIdx.x * blockDim.x + threadIdx.x;
  if (e < NE) atomicAdd(&deg[dstv[e]], 1);
}

__global__ __launch_bounds__(256) void k_scanA(const int* __restrict__ deg, int* __restrict__ part) {
  int b = blockIdx.x, t = threadIdx.x;
  int s = 0;
  for (int j = t; j < 1024; j += 256) { int i = b * 1024 + j; if (i < NN) s += deg[i]; }
  __shared__ int sh[4];
  for (int o = 32; o; o >>= 1) s += __shfl_down(s, o, 64);
  if ((t & 63) == 0) sh[t >> 6] = s;
  __syncthreads();
  if (t == 0) part[b] = sh[0] + sh[1] + sh[2] + sh[3];
}

__global__ void k_scanB(int* __restrict__ part, int* __restrict__ row_ptr) {
  if (threadIdx.x == 0 && blockIdx.x == 0) {
    int run = 0;
    for (int i = 0; i < NCH; ++i) { int v = part[i]; part[i] = run; run += v; }
    row_ptr[NN] = run;
  }
}

__global__ __launch_bounds__(1024) void k_scanC(const int* __restrict__ deg, const int* __restrict__ part,
                                                int* __restrict__ row_ptr, int* __restrict__ cursor) {
  __shared__ int buf[1024];
  int b = blockIdx.x, t = threadIdx.x;
  int i = b * 1024 + t;
  int v = (i < NN) ? deg[i] : 0;
  buf[t] = v;
  __syncthreads();
  for (int off = 1; off < 1024; off <<= 1) {
    int add = (t >= off) ? buf[t - off] : 0;
    __syncthreads();
    buf[t] += add;
    __syncthreads();
  }
  if (i < NN) { int ex = part[b] + buf[t] - v; row_ptr[i] = ex; cursor[i] = ex; }
}

// col stores BYTE offsets of kv rows (src * 512)
__global__ void k_scatter(const int* __restrict__ srcv, const int* __restrict__ dstv,
                          int* __restrict__ cursor, uint* __restrict__ colb) {
  int e = blockIdx.x * blockDim.x + threadIdx.x;
  if (e < NE) {
    int d = dstv[e];
    int pos = atomicAdd(&cursor[d], 1);
    colb[pos] = ((uint)srcv[e]) << 9;
  }
}

// ---------------- weight preconvert: fragment-order tiles ----------------
__device__ __forceinline__ size_t wtile_idx(int k, int c) {
  return (size_t)(k >> 5) * 4096 + ((((c >> 4) * 4 + ((k & 31) >> 3)) * 16 + (c & 15)) * 8 + (k & 7));
}

__global__ __launch_bounds__(256) void k_wconv0(const float* __restrict__ W0, const float* __restrict__ W1,
                                                const float* __restrict__ W2, const float* __restrict__ W3,
                                                ushort* __restrict__ wh, ushort* __restrict__ wl) {
  int id = blockIdx.x * 256 + threadIdx.x;           // 4*64*128 = 32768
  if (id >= 4 * 64 * 128) return;
  int mat = id >> 13, rem = id & 8191;
  int k = rem >> 7, c = rem & 127;
  const float* W = (mat == 0) ? W0 : (mat == 1) ? W1 : (mat == 2) ? W2 : W3;
  float v = W[k * 128 + c];
  ushort h = f2bf(v);
  ushort lo = f2bf(v - bf2f(h));
  size_t dst = (size_t)mat * 8192 + wtile_idx(k, c);
  wh[dst] = h; wl[dst] = lo;
}

__global__ __launch_bounds__(256) void k_wconvS(const float* __restrict__ Wq, const float* __restrict__ Wk,
                                                const float* __restrict__ Wv, const float* __restrict__ Ws,
                                                ushort* __restrict__ wh, ushort* __restrict__ wl) {
  int id = blockIdx.x * 256 + threadIdx.x;           // 5*4*128*128 = 327680
  if (id >= 5 * 4 * 16384) return;
  int lay = id / 65536, rem = id % 65536;
  int mat = rem >> 14, rem2 = rem & 16383;
  int k = rem2 >> 7, c = rem2 & 127;
  const float* W = (mat == 0) ? Wq : (mat == 1) ? Wk : (mat == 2) ? Wv : Ws;
  float v = W[(size_t)lay * 16384 + k * 128 + c];
  ushort h = f2bf(v);
  ushort lo = f2bf(v - bf2f(h));
  size_t dst = 32768 + ((size_t)lay * 4 + mat) * 16384 + wtile_idx(k, c);
  wh[dst] = h; wl[dst] = lo;
}

// ---------------- presplit (layer-0 input only): split-bf16, fragment-order tiled ----------------
template <int K>
__global__ __launch_bounds__(256) void k_presplit(const float* __restrict__ Y,
                                                  ushort* __restrict__ Xh, ushort* __restrict__ Xl) {
  const int CP = K / 4;
  int idx = blockIdx.x * 256 + threadIdx.x;
  int row = idx / CP;
  int c4 = (idx % CP) * 4;
  if (row >= NN) return;
  float4 v = *reinterpret_cast<const float4*>(Y + (size_t)row * K + c4);
  ushort h0 = f2bf(v.x), h1 = f2bf(v.y), h2 = f2bf(v.z), h3 = f2bf(v.w);
  ushort l0 = f2bf(v.x - bf2f(h0)), l1 = f2bf(v.y - bf2f(h1));
  ushort l2 = f2bf(v.z - bf2f(h2)), l3 = f2bf(v.w - bf2f(h3));
  int b = row >> 7, g = (row & 127) >> 4, frow = row & 15;
  int ks = c4 >> 5, qq = (c4 & 31) >> 3, j = c4 & 7;
  size_t base = ((size_t)ks * NB + b) * 4096 + (((g * 4 + qq) * 16) + frow) * 8 + j;
  *reinterpret_cast<uint2*>(Xh + base) =
      make_uint2((uint)h0 | ((uint)h1 << 16), (uint)h2 | ((uint)h3 << 16));
  *reinterpret_cast<uint2*>(Xl + base) =
      make_uint2((uint)l0 | ((uint)l1 << 16), (uint)l2 | ((uint)l3 << 16));
}

// ---------------- MFMA GEMM (pre-split A and B, global_load_lds staging) ----------------
// Flattened grid with XCD-coherent A-sharing. Uniform 3-pass split (R7-proven).
// mat 0 -> q (bf16, pre-scaled), mat 1 -> k half of kv, mat 2 -> v half, mat 3 -> xs (bf16 packed)
template <int K>
__global__ __launch_bounds__(256, 2) void k_gemm(
    const ushort* __restrict__ Xh, const ushort* __restrict__ Xl,
    const ushort* __restrict__ Wth, const ushort* __restrict__ Wtl,
    const float* __restrict__ b0, const float* __restrict__ b1,
    const float* __restrict__ b2, const float* __restrict__ b3,
    ushort* __restrict__ qbf, ushort* __restrict__ kv, ushort* __restrict__ xsb) {
  __shared__ __align__(16) ushort Ah[4096];
  __shared__ __align__(16) ushort Al[4096];
  __shared__ __align__(16) ushort Bh[4096];
  __shared__ __align__(16) ushort Bl[4096];
  int bid = blockIdx.x;
  int mat = (bid >> 3) & 3;
  int b = (bid & 7) + ((bid >> 5) << 3);
  if (b >= NB) return;
  int t = threadIdx.x;
  int lane = t & 63, w = t >> 6;
  int wr = w >> 1, wc = w & 1;
  int frow = lane & 15;
  const ushort* wh = Wth + (size_t)mat * (K * 128);
  const ushort* wl = Wtl + (size_t)mat * (K * 128);
  const float* bb = (mat == 0) ? b0 : (mat == 1) ? b1 : (mat == 2) ? b2 : b3;

  f32x4 acc[4][4];
#pragma unroll
  for (int i = 0; i < 4; ++i)
#pragma unroll
    for (int j = 0; j < 4; ++j)
#pragma unroll
      for (int r = 0; r < 4; ++r) acc[i][j][r] = 0.f;

  int wofs = w * 1024 + lane * 8;
  for (int ks = 0; ks < K / 32; ++ks) {
    size_t abase = ((size_t)ks * NB + b) * 4096;
    const ushort* gAh = Xh + abase + wofs;
    const ushort* gAl = Xl + abase + wofs;
    const ushort* gBh = wh + ks * 4096 + wofs;
    const ushort* gBl = wl + ks * 4096 + wofs;
    gload16(gAh, &Ah[w * 1024]);
    gload16(gAh + 512, &Ah[w * 1024 + 512]);
    gload16(gAl, &Al[w * 1024]);
    gload16(gAl + 512, &Al[w * 1024 + 512]);
    gload16(gBh, &Bh[w * 1024]);
    gload16(gBh + 512, &Bh[w * 1024 + 512]);
    gload16(gBl, &Bl[w * 1024]);
    gload16(gBl + 512, &Bl[w * 1024 + 512]);
    __syncthreads();
    s16x8 ah[4], al[4], bh[4], bl[4];
#pragma unroll
    for (int g = 0; g < 4; ++g) {
      ah[g] = *reinterpret_cast<const s16x8*>(&Ah[(wr * 4 + g) * 512 + lane * 8]);
      al[g] = *reinterpret_cast<const s16x8*>(&Al[(wr * 4 + g) * 512 + lane * 8]);
      bh[g] = *reinterpret_cast<const s16x8*>(&Bh[(wc * 4 + g) * 512 + lane * 8]);
      bl[g] = *reinterpret_cast<const s16x8*>(&Bl[(wc * 4 + g) * 512 + lane * 8]);
    }
#pragma unroll
    for (int rg = 0; rg < 4; ++rg)
#pragma unroll
      for (int cg = 0; cg < 4; ++cg) {
        acc[rg][cg] = __builtin_amdgcn_mfma_f32_16x16x32_bf16(ah[rg], bh[cg], acc[rg][cg], 0, 0, 0);
        acc[rg][cg] = __builtin_amdgcn_mfma_f32_16x16x32_bf16(al[rg], bh[cg], acc[rg][cg], 0, 0, 0);
        acc[rg][cg] = __builtin_amdgcn_mfma_f32_16x16x32_bf16(ah[rg], bl[cg], acc[rg][cg], 0, 0, 0);
      }
    __syncthreads();
  }
  int r0 = b * 128;
  int qq = (lane >> 4) << 2;
#pragma unroll
  for (int rg = 0; rg < 4; ++rg) {
#pragma unroll
    for (int cg = 0; cg < 4; ++cg) {
      int colg = wc * 64 + cg * 16 + frow;
      float bv = bb[colg];
#pragma unroll
      for (int r = 0; r < 4; ++r) {
        int row = r0 + wr * 64 + rg * 16 + qq + r;
        if (row >= NN) continue;
        float val = acc[rg][cg][r] + bv;
        if (mat == 0)      qbf[(size_t)row * FHH + colg] = f2bf(val * QSCALE);
        else if (mat == 3) xsb[(size_t)row * FHH + colg] = f2bf(val);
        else {
          int pos = (colg >> 1) * 4 + ((mat == 2) ? 2 : 0) + (colg & 1);
          kv[(size_t)row * 256 + pos] = f2bf(val);
        }
      }
    }
  }
}

// ---------------- node-centric softmax aggregate ----------------
// NEW: 4 features/lane, 32 lanes per edge, TWO edges per wave (half-waves).
// kv row chunk at lane j (16B) = {k(4j),k(4j+1), v(4j),v(4j+1), k(4j+2),k(4j+3), v(4j+2),v(4j+3)}.
// Head = 4-lane group; cross-half combine once per node. 4 nodes per 256-block, no barriers.
__global__ __launch_bounds__(256) void k_agg(const uint* __restrict__ qb,
                                             const ushort* __restrict__ kv,
                                             const uint* __restrict__ xsb,
                                             const int* __restrict__ row_ptr,
                                             const uint* __restrict__ colb,
                                             uint* __restrict__ yb) {
  int n = blockIdx.x * 4 + (threadIdx.x >> 6);
  int lane = threadIdx.x & 63;
  int hl = lane & 31, half = lane >> 5;
  uint2 qp = *reinterpret_cast<const uint2*>(qb + (n << 6) + 2 * hl);
#if !HAVE_BFDOT
  float qa = bfl(qp.x), qbv = bfh(qp.x), qc = bfl(qp.y), qd = bfh(qp.y);
#endif
  const char* kvb = (const char*)kv;
  uint tof = (uint)hl * 16u;
  int e0 = row_ptr[n], e1 = row_ptr[n + 1];
  float sum = 0.f, a0 = 0.f, a1 = 0.f, a2 = 0.f, a3 = 0.f;
  int i = e0;
  for (; i + 4 <= e1; i += 4) {
    uint oA = colb[i + half] + tof;
    uint oB = colb[i + 2 + half] + tof;
    uint4 dA = *(const uint4*)(kvb + oA);
    uint4 dB = *(const uint4*)(kvb + oB);
#if HAVE_BFDOT
    float pA = dot2acc(dA.z, qp.y, dot2acc(dA.x, qp.x, 0.f));
    float pB = dot2acc(dB.z, qp.y, dot2acc(dB.x, qp.x, 0.f));
#else
    float pA = qa * bfl(dA.x);
    pA = fmaf(qbv, bfh(dA.x), pA);
    pA = fmaf(qc, bfl(dA.z), pA);
    pA = fmaf(qd, bfh(dA.z), pA);
    float pB = qa * bfl(dB.x);
    pB = fmaf(qbv, bfh(dB.x), pB);
    pB = fmaf(qc, bfl(dB.z), pB);
    pB = fmaf(qd, bfh(dB.z), pB);
#endif
    pA += __shfl_xor(pA, 1, 4);  pB += __shfl_xor(pB, 1, 4);
    pA += __shfl_xor(pA, 2, 4);  pB += __shfl_xor(pB, 2, 4);
    float wA = exp2f(fminf(pA, 110.f));
    float wB = exp2f(fminf(pB, 110.f));
    sum += wA + wB;
    a0 = fmaf(wA, bfl(dA.y), fmaf(wB, bfl(dB.y), a0));
    a1 = fmaf(wA, bfh(dA.y), fmaf(wB, bfh(dB.y), a1));
    a2 = fmaf(wA, bfl(dA.w), fmaf(wB, bfl(dB.w), a2));
    a3 = fmaf(wA, bfh(dA.w), fmaf(wB, bfh(dB.w), a3));
  }
  for (; i + 2 <= e1; i += 2) {
    uint oA = colb[i + half] + tof;
    uint4 dA = *(const uint4*)(kvb + oA);
#if HAVE_BFDOT
    float pA = dot2acc(dA.z, qp.y, dot2acc(dA.x, qp.x, 0.f));
#else
    float pA = qa * bfl(dA.x);
    pA = fmaf(qbv, bfh(dA.x), pA);
    pA = fmaf(qc, bfl(dA.z), pA);
    pA = fmaf(qd, bfh(dA.z), pA);
#endif
    pA += __shfl_xor(pA, 1, 4);
    pA += __shfl_xor(pA, 2, 4);
    float wA = exp2f(fminf(pA, 110.f));
    sum += wA;
    a0 = fmaf(wA, bfl(dA.y), a0);
    a1 = fmaf(wA, bfh(dA.y), a1);
    a2 = fmaf(wA, bfl(dA.w), a2);
    a3 = fmaf(wA, bfh(dA.w), a3);
  }
  if (i < e1) {
    uint oA = colb[i] + tof;
    uint4 dA = *(const uint4*)(kvb + oA);
#if HAVE_BFDOT
    float pA = dot2acc(dA.z, qp.y, dot2acc(dA.x, qp.x, 0.f));
#else
    float pA = qa * bfl(dA.x);
    pA = fmaf(qbv, bfh(dA.x), pA);
    pA = fmaf(qc, bfl(dA.z), pA);
    pA = fmaf(qd, bfh(dA.z), pA);
#endif
    pA += __shfl_xor(pA, 1, 4);
    pA += __shfl_xor(pA, 2, 4);
    float wA = exp2f(fminf(pA, 110.f));
    if (half) wA = 0.f;           // only one real edge; second half contributes nothing
    sum += wA;
    a0 = fmaf(wA, bfl(dA.y), a0);
    a1 = fmaf(wA, bfh(dA.y), a1);
    a2 = fmaf(wA, bfl(dA.w), a2);
    a3 = fmaf(wA, bfh(dA.w), a3);
  }
  // cross-half combine (even edges in half 0, odd in half 1)
  sum += __shfl_xor(sum, 32);
  a0 += __shfl_xor(a0, 32);
  a1 += __shfl_xor(a1, 32);
  a2 += __shfl_xor(a2, 32);
  a3 += __shfl_xor(a3, 32);
  float inv = 1.f / fmaxf(sum, 1e-16f);
  uint2 xv = *reinterpret_cast<const uint2*>(xsb + (n << 6) + 2 * hl);
  float o0 = fmaf(a0, inv, bfl(xv.x));
  float o1 = fmaf(a1, inv, bfh(xv.x));
  float o2 = fmaf(a2, inv, bfl(xv.y));
  float o3 = fmaf(a3, inv, bfh(xv.y));
  if (half == 0) {
    uint2 o;
    o.x = packbf(o0, o1);
    o.y = packbf(o2, o3);
    *reinterpret_cast<uint2*>(yb + (n << 6) + 2 * hl) = o;
  }
}

// ---------------- BN statistics (packed bf16 y) ----------------
__global__ __launch_bounds__(256) void k_bnstats(const uint* __restrict__ yb,
                                                 float* __restrict__ stats) {
  __shared__ float2 s1[256], s2[256];
  int u = threadIdx.x & 63;
  int grp = threadIdx.x >> 6;
  float2 a = make_float2(0.f, 0.f), b = make_float2(0.f, 0.f);
  for (int r = blockIdx.x * 4 + grp; r < NN; r += 1024) {
    uint d = yb[(size_t)r * 64 + u];
    float x = bfl(d), yv = bfh(d);
    a.x += x; a.y += yv;
    b.x = fmaf(x, x, b.x); b.y = fmaf(yv, yv, b.y);
  }
  s1[threadIdx.x] = a;
  s2[threadIdx.x] = b;
  __syncthreads();
  if (grp == 0) {
#pragma unroll
    for (int g = 1; g < 4; ++g) {
      a.x += s1[u + 64 * g].x; a.y += s1[u + 64 * g].y;
      b.x += s2[u + 64 * g].x; b.y += s2[u + 64 * g].y;
    }
    atomicAdd(&stats[2 * u], a.x);
    atomicAdd(&stats[2 * u + 1], a.y);
    atomicAdd(&stats[128 + 2 * u], b.x);
    atomicAdd(&stats[128 + 2 * u + 1], b.y);
  }
}

// ---------------- fused post: BN+ReLU once -> (pool atomic means) + (split-bf16 fragment write) ----------
template <int WRITE_X>
__global__ __launch_bounds__(256) void k_post(const uint* __restrict__ yb,
                                              const float* __restrict__ st,
                                              const float* __restrict__ gvec,
                                              const float* __restrict__ bvec_,
                                              const int* __restrict__ bv,
                                              const int* __restrict__ gstart,
                                              float* __restrict__ out, int layer,
                                              ushort* __restrict__ Xh, ushort* __restrict__ Xl) {
  __shared__ float acts[8][128];
  __shared__ int sg[8];
  __shared__ float ssc[128], ssh[128];
  int b = blockIdx.x, t = threadIdx.x;
  if (t < 128) {
    const float invn = 1.f / (float)NN;
    float mu = st[t] * invn;
    float var = st[128 + t] * invn - mu * mu;
    float sc = gvec[t] * rsqrtf(var + 1e-5f);
    ssc[t] = sc;
    ssh[t] = bvec_[t] - mu * sc;
  }
  if (t < 8) sg[t] = (b * 8 + t < NN) ? bv[b * 8 + t] : -1;
  __syncthreads();
  int row = b * 8 + (t >> 5);
  int c4 = (t & 31) * 4;
  bool ok = row < NN;
  float4 a = make_float4(0.f, 0.f, 0.f, 0.f);
  if (ok) {
    uint2 u2 = *reinterpret_cast<const uint2*>(yb + (size_t)row * 64 + (c4 >> 1));
    a.x = fmaxf(fmaf(bfl(u2.x), ssc[c4 + 0], ssh[c4 + 0]), 0.f);
    a.y = fmaxf(fmaf(bfh(u2.x), ssc[c4 + 1], ssh[c4 + 1]), 0.f);
    a.z = fmaxf(fmaf(bfl(u2.y), ssc[c4 + 2], ssh[c4 + 2]), 0.f);
    a.w = fmaxf(fmaf(bfh(u2.y), ssc[c4 + 3], ssh[c4 + 3]), 0.f);
  }
  *reinterpret_cast<float4*>(&acts[t >> 5][c4]) = a;
  if (WRITE_X && ok) {
    ushort h0 = f2bf(a.x), h1 = f2bf(a.y), h2 = f2bf(a.z), h3 = f2bf(a.w);
    ushort l0 = f2bf(a.x - bf2f(h0)), l1 = f2bf(a.y - bf2f(h1));
    ushort l2 = f2bf(a.z - bf2f(h2)), l3 = f2bf(a.w - bf2f(h3));
    int bb = row >> 7, g = (row & 127) >> 4, frow = row & 15;
    int ks = c4 >> 5, qq = (c4 & 31) >> 3, j = c4 & 7;
    size_t base = ((size_t)ks * NB + bb) * 4096 + (((g * 4 + qq) * 16) + frow) * 8 + j;
    *reinterpret_cast<uint2*>(Xh + base) =
        make_uint2((uint)h0 | ((uint)h1 << 16), (uint)h2 | ((uint)h3 << 16));
    *reinterpret_cast<uint2*>(Xl + base) =
        make_uint2((uint)l0 | ((uint)l1 << 16), (uint)l2 | ((uint)l3 << 16));
  }
  __syncthreads();
  if (t < 128) {
    float racc = 0.f;
    int cg = sg[0];
    for (int r = 0; r < 8; ++r) {
      int g = sg[r];
      if (g != cg) {
        if (cg >= 0) {
          float p = racc / (float)(gstart[cg + 1] - gstart[cg]);
          if (layer < 5) atomicAdd(&out[(size_t)cg * 1024 + layer * FHH + t], p);
          else {
            atomicAdd(&out[(size_t)cg * 1024 + 5 * FHH + t], p);
            atomicAdd(&out[(size_t)cg * 1024 + 6 * FHH + t], p);
            atomicAdd(&out[(size_t)cg * 1024 + 7 * FHH + t], p);
          }
        }
        racc = 0.f;
        cg = g;
      }
      racc += acts[r][t];
    }
    if (cg >= 0) {
      float p = racc / (float)(gstart[cg + 1] - gstart[cg]);
      if (layer < 5) atomicAdd(&out[(size_t)cg * 1024 + layer * FHH + t], p);
      else {
        atomicAdd(&out[(size_t)cg * 1024 + 5 * FHH + t], p);
        atomicAdd(&out[(size_t)cg * 1024 + 6 * FHH + t], p);
        atomicAdd(&out[(size_t)cg * 1024 + 7 * FHH + t], p);
      }
    }
  }
}

extern "C" void kernel_launch(void* const* d_in, const int* in_sizes, int n_in,
                              void* d_out, int out_size, void* d_ws, size_t ws_size,
                              hipStream_t stream) {
  (void)in_sizes; (void)n_in; (void)ws_size;
  const float* x    = (const float*)d_in[0];
  const int*   ei   = (const int*)d_in[1];
  const int*   bvec = (const int*)d_in[2];
  const float* Wq0  = (const float*)d_in[3];
  const float* bq0  = (const float*)d_in[4];
  const float* Wk0  = (const float*)d_in[5];
  const float* bk0  = (const float*)d_in[6];
  const float* Wv0  = (const float*)d_in[7];
  const float* bv0  = (const float*)d_in[8];
  const float* Ws0  = (const float*)d_in[9];
  const float* bs0  = (const float*)d_in[10];
  const float* WqS  = (const float*)d_in[11];
  const float* bqS  = (const float*)d_in[12];
  const float* WkS  = (const float*)d_in[13];
  const float* bkS  = (const float*)d_in[14];
  const float* WvS  = (const float*)d_in[15];
  const float* bvS  = (const float*)d_in[16];
  const float* WsS  = (const float*)d_in[17];
  const float* bsS  = (const float*)d_in[18];
  const float* gamma = (const float*)d_in[19];
  const float* beta  = (const float*)d_in[20];
  float* out = (float*)d_out;

  char* ws = (char*)d_ws;
  size_t off = 0;
  auto alloc = [&](size_t bytes) {
    void* p = ws + off;
    off = (off + bytes + 255) & ~(size_t)255;
    return p;
  };
  ushort* qbf = (ushort*)alloc((size_t)NN * FHH * 2);
  ushort* xsb = (ushort*)alloc((size_t)NN * FHH * 2);
  uint* yb    = (uint*)alloc((size_t)NN * 64 * 4);
  ushort* kv  = (ushort*)alloc((size_t)NN * 256 * 2);
  ushort* Xh  = (ushort*)alloc((size_t)4 * NB * 4096 * 2 + 8192);
  ushort* Xl  = (ushort*)alloc((size_t)4 * NB * 4096 * 2 + 8192);
  uint* colb   = (uint*)alloc((size_t)NE * 4);
  int* row_ptr = (int*)alloc((size_t)(NN + 1) * 4);
  int* cursor  = (int*)alloc((size_t)NN * 4);
  int* deg     = (int*)alloc((size_t)NN * 4);
  int* part    = (int*)alloc((size_t)NCH * 4);
  int* gstart  = (int*)alloc((size_t)(NG + 1) * 4);
  float* bstat = (float*)alloc((size_t)NL * 2 * FHH * 4);   // [layer][{sum,sumsq}][128]
  ushort* wsh = (ushort*)alloc((size_t)360448 * 2);
  ushort* wsl = (ushort*)alloc((size_t)360448 * 2);

  const int* srcv = ei;
  const int* dstv = ei + NE;

  hipMemsetAsync(out, 0, (size_t)out_size * 4, stream);
  hipMemsetAsync(deg, 0, (size_t)NN * 4, stream);
  hipMemsetAsync(bstat, 0, (size_t)NL * 2 * FHH * 4, stream);
  k_gstart<<<5, 64, 0, stream>>>(bvec, gstart);
  k_deg<<<(NE + 255) / 256, 256, 0, stream>>>(dstv, deg);
  k_scanA<<<NCH, 256, 0, stream>>>(deg, part);
  k_scanB<<<1, 64, 0, stream>>>(part, row_ptr);
  k_scanC<<<NCH, 1024, 0, stream>>>(deg, part, row_ptr, cursor);
  k_scatter<<<(NE + 255) / 256, 256, 0, stream>>>(srcv, dstv, cursor, colb);
  k_wconv0<<<128, 256, 0, stream>>>(Wq0, Wk0, Wv0, Ws0, wsh, wsl);
  k_wconvS<<<1280, 256, 0, stream>>>(WqS, WkS, WvS, WsS, wsh, wsl);
  k_presplit<64><<<(NN * 16 + 255) / 256, 256, 0, stream>>>(x, Xh, Xl);

  const int GEMM_GRID = 49 * 32;   // ceil(NB/8)*32 : 4 mats x NB blocks, XCD-swizzled
  for (int l = 0; l < NL; ++l) {
    const ushort* WthL = wsh + ((l == 0) ? 0 : (size_t)32768 + (size_t)(l - 1) * 65536);
    const ushort* WtlL = wsl + ((l == 0) ? 0 : (size_t)32768 + (size_t)(l - 1) * 65536);
    const float *bq_, *bk_, *bv_, *bs_;
    if (l == 0) { bq_ = bq0; bk_ = bk0; bv_ = bv0; bs_ = bs0; }
    else {
      size_t bo = (size_t)(l - 1) * FHH;
      bq_ = bqS + bo; bk_ = bkS + bo; bv_ = bvS + bo; bs_ = bsS + bo;
    }
    if (l == 0)
      k_gemm<64><<<GEMM_GRID, 256, 0, stream>>>(Xh, Xl, WthL, WtlL, bq_, bk_, bv_, bs_, qbf, kv, xsb);
    else
      k_gemm<128><<<GEMM_GRID, 256, 0, stream>>>(Xh, Xl, WthL, WtlL, bq_, bk_, bv_, bs_, qbf, kv, xsb);
    k_agg<<<NN / 4, 256, 0, stream>>>((const uint*)qbf, kv, (const uint*)xsb, row_ptr, colb, yb);
    float* lstat = bstat + (size_t)l * 2 * FHH;
    k_bnstats<<<256, 256, 0, stream>>>(yb, lstat);
    if (l + 1 < NL)
      k_post<1><<<6250, 256, 0, stream>>>(yb, lstat, gamma + (size_t)l * FHH,
                                          beta + (size_t)l * FHH, bvec, gstart, out, l, Xh, Xl);
    else
      k_post<0><<<6250, 256, 0, stream>>>(yb, lstat, gamma + (size_t)l * FHH,
                                          beta + (size_t)l * FHH, bvec, gstart, out, l, Xh, Xl);
  }
}

// Round 11
// 901.328 us; speedup vs baseline: 1.1579x; 1.0445x over previous
//
#include <hip/hip_runtime.h>
#include <hip/hip_bf16.h>
#include <math.h>

#define NN 50000
#define NE 800000
#define NG 256
#define FHH 128
#define NL 6
#define NCH 49    // ceil(50000/1024)
#define NB 391    // ceil(50000/128) row-blocks

typedef __attribute__((ext_vector_type(8))) short s16x8;
typedef __attribute__((ext_vector_type(4))) float f32x4;

#define QSCALE 0.36067376022224085f   // 0.25 * log2(e)

#if defined(__has_builtin)
#if __has_builtin(__builtin_amdgcn_fdot2_f32_bf16)
#define HAVE_BFDOT 1
#endif
#endif
#ifndef HAVE_BFDOT
#define HAVE_BFDOT 0
#endif

__device__ __forceinline__ ushort f2bf(float x) {
  uint u = __float_as_uint(x);
  u += 0x7fffu + ((u >> 16) & 1u);
  return (ushort)(u >> 16);
}
__device__ __forceinline__ float bf2f(ushort h) {
  return __uint_as_float(((uint)h) << 16);
}
__device__ __forceinline__ float bfl(uint u) { return __uint_as_float(u << 16); }
__device__ __forceinline__ float bfh(uint u) { return __uint_as_float(u & 0xffff0000u); }
__device__ __forceinline__ uint packbf(float a, float b) {
  return (uint)f2bf(a) | ((uint)f2bf(b) << 16);
}

#if HAVE_BFDOT
typedef __attribute__((ext_vector_type(2))) __bf16 bf16v2;
__device__ __forceinline__ float dot2acc(uint a, uint b, float acc) {
  return __builtin_amdgcn_fdot2_f32_bf16(__builtin_bit_cast(bf16v2, a),
                                         __builtin_bit_cast(bf16v2, b), acc, false);
}
#endif

__device__ __forceinline__ void gload16(const ushort* g, ushort* l) {
  __builtin_amdgcn_global_load_lds(
      (const __attribute__((address_space(1))) uint*)(const void*)g,
      (__attribute__((address_space(3))) uint*)(void*)l, 16, 0, 0);
}

// ---------------- graph-boundary search (batch_vec sorted) ----------------
__global__ void k_gstart(const int* __restrict__ bv, int* __restrict__ gstart) {
  int g = blockIdx.x * blockDim.x + threadIdx.x;
  if (g > NG) return;
  int lo = 0, hi = NN;
  while (lo < hi) { int mid = (lo + hi) >> 1; if (bv[mid] < g) lo = mid + 1; else hi = mid; }
  gstart[g] = lo;
}

// ---------------- CSR build (by dst) ----------------
__global__ void k_deg(const int* __restrict__ dstv, int* __restrict__ deg) {
  int e = blockIdx.x * blockDim.x + threadIdx.x;
  if (e < NE) atomicAdd(&deg[dstv[e]], 1);
}

__global__ __launch_bounds__(256) void k_scanA(const int* __restrict__ deg, int* __restrict__ part) {
  int b = blockIdx.x, t = threadIdx.x;
  int s = 0;
  for (int j = t; j < 1024; j += 256) { int i = b * 1024 + j; if (i < NN) s += deg[i]; }
  __shared__ int sh[4];
  for (int o = 32; o; o >>= 1) s += __shfl_down(s, o, 64);
  if ((t & 63) == 0) sh[t >> 6] = s;
  __syncthreads();
  if (t == 0) part[b] = sh[0] + sh[1] + sh[2] + sh[3];
}

__global__ void k_scanB(int* __restrict__ part, int* __restrict__ row_ptr) {
  if (threadIdx.x == 0 && blockIdx.x == 0) {
    int run = 0;
    for (int i = 0; i < NCH; ++i) { int v = part[i]; part[i] = run; run += v; }
    row_ptr[NN] = run;
  }
}

__global__ __launch_bounds__(1024) void k_scanC(const int* __restrict__ deg, const int* __restrict__ part,
                                                int* __restrict__ row_ptr, int* __restrict__ cursor) {
  __shared__ int buf[1024];
  int b = blockIdx.x, t = threadIdx.x;
  int i = b * 1024 + t;
  int v = (i < NN) ? deg[i] : 0;
  buf[t] = v;
  __syncthreads();
  for (int off = 1; off < 1024; off <<= 1) {
    int add = (t >= off) ? buf[t - off] : 0;
    __syncthreads();
    buf[t] += add;
    __syncthreads();
  }
  if (i < NN) { int ex = part[b] + buf[t] - v; row_ptr[i] = ex; cursor[i] = ex; }
}

// col stores BYTE offsets of kv rows (src * 512)
__global__ void k_scatter(const int* __restrict__ srcv, const int* __restrict__ dstv,
                          int* __restrict__ cursor, uint* __restrict__ colb) {
  int e = blockIdx.x * blockDim.x + threadIdx.x;
  if (e < NE) {
    int d = dstv[e];
    int pos = atomicAdd(&cursor[d], 1);
    colb[pos] = ((uint)srcv[e]) << 9;
  }
}

// ---------------- weight preconvert: fragment-order tiles ----------------
__device__ __forceinline__ size_t wtile_idx(int k, int c) {
  return (size_t)(k >> 5) * 4096 + ((((c >> 4) * 4 + ((k & 31) >> 3)) * 16 + (c & 15)) * 8 + (k & 7));
}

__global__ __launch_bounds__(256) void k_wconv0(const float* __restrict__ W0, const float* __restrict__ W1,
                                                const float* __restrict__ W2, const float* __restrict__ W3,
                                                ushort* __restrict__ wh, ushort* __restrict__ wl) {
  int id = blockIdx.x * 256 + threadIdx.x;           // 4*64*128 = 32768
  if (id >= 4 * 64 * 128) return;
  int mat = id >> 13, rem = id & 8191;
  int k = rem >> 7, c = rem & 127;
  const float* W = (mat == 0) ? W0 : (mat == 1) ? W1 : (mat == 2) ? W2 : W3;
  float v = W[k * 128 + c];
  ushort h = f2bf(v);
  ushort lo = f2bf(v - bf2f(h));
  size_t dst = (size_t)mat * 8192 + wtile_idx(k, c);
  wh[dst] = h; wl[dst] = lo;
}

__global__ __launch_bounds__(256) void k_wconvS(const float* __restrict__ Wq, const float* __restrict__ Wk,
                                                const float* __restrict__ Wv, const float* __restrict__ Ws,
                                                ushort* __restrict__ wh, ushort* __restrict__ wl) {
  int id = blockIdx.x * 256 + threadIdx.x;           // 5*4*128*128 = 327680
  if (id >= 5 * 4 * 16384) return;
  int lay = id / 65536, rem = id % 65536;
  int mat = rem >> 14, rem2 = rem & 16383;
  int k = rem2 >> 7, c = rem2 & 127;
  const float* W = (mat == 0) ? Wq : (mat == 1) ? Wk : (mat == 2) ? Wv : Ws;
  float v = W[(size_t)lay * 16384 + k * 128 + c];
  ushort h = f2bf(v);
  ushort lo = f2bf(v - bf2f(h));
  size_t dst = 32768 + ((size_t)lay * 4 + mat) * 16384 + wtile_idx(k, c);
  wh[dst] = h; wl[dst] = lo;
}

// ---------------- presplit (layer-0 input only): bf16-high, fragment-order tiled ----------------
template <int K>
__global__ __launch_bounds__(256) void k_presplit(const float* __restrict__ Y,
                                                  ushort* __restrict__ Xh) {
  const int CP = K / 4;
  int idx = blockIdx.x * 256 + threadIdx.x;
  int row = idx / CP;
  int c4 = (idx % CP) * 4;
  if (row >= NN) return;
  float4 v = *reinterpret_cast<const float4*>(Y + (size_t)row * K + c4);
  ushort h0 = f2bf(v.x), h1 = f2bf(v.y), h2 = f2bf(v.z), h3 = f2bf(v.w);
  int b = row >> 7, g = (row & 127) >> 4, frow = row & 15;
  int ks = c4 >> 5, qq = (c4 & 31) >> 3, j = c4 & 7;
  size_t base = ((size_t)ks * NB + b) * 4096 + (((g * 4 + qq) * 16) + frow) * 8 + j;
  *reinterpret_cast<uint2*>(Xh + base) =
      make_uint2((uint)h0 | ((uint)h1 << 16), (uint)h2 | ((uint)h3 << 16));
}

// ---------------- MFMA GEMM (2-pass: ah*bh + ah*bl; weight-low kept, activation-low dropped) -----
// Flattened grid with XCD-coherent A-sharing: bids {c, c+8, c+16, c+24} cover the
// 4 mats of one row-block and land on the same XCD -> A L2 hits.
// mat 0 -> q (bf16, pre-scaled), mat 1 -> k half of kv, mat 2 -> v half, mat 3 -> xs (bf16)
template <int K>
__global__ __launch_bounds__(256, 3) void k_gemm(
    const ushort* __restrict__ Xh,
    const ushort* __restrict__ Wth, const ushort* __restrict__ Wtl,
    const float* __restrict__ b0, const float* __restrict__ b1,
    const float* __restrict__ b2, const float* __restrict__ b3,
    ushort* __restrict__ qbf, ushort* __restrict__ kv, ushort* __restrict__ xsb) {
  __shared__ __align__(16) ushort Ah[4096];
  __shared__ __align__(16) ushort Bh[4096];
  __shared__ __align__(16) ushort Bl[4096];
  int bid = blockIdx.x;
  int mat = (bid >> 3) & 3;
  int b = (bid & 7) + ((bid >> 5) << 3);
  if (b >= NB) return;
  int t = threadIdx.x;
  int lane = t & 63, w = t >> 6;
  int wr = w >> 1, wc = w & 1;
  int frow = lane & 15;
  const ushort* wh = Wth + (size_t)mat * (K * 128);
  const ushort* wl = Wtl + (size_t)mat * (K * 128);
  const float* bb = (mat == 0) ? b0 : (mat == 1) ? b1 : (mat == 2) ? b2 : b3;

  f32x4 acc[4][4];
#pragma unroll
  for (int i = 0; i < 4; ++i)
#pragma unroll
    for (int j = 0; j < 4; ++j)
#pragma unroll
      for (int r = 0; r < 4; ++r) acc[i][j][r] = 0.f;

  int wofs = w * 1024 + lane * 8;
  for (int ks = 0; ks < K / 32; ++ks) {
    size_t abase = ((size_t)ks * NB + b) * 4096;
    const ushort* gAh = Xh + abase + wofs;
    const ushort* gBh = wh + ks * 4096 + wofs;
    const ushort* gBl = wl + ks * 4096 + wofs;
    gload16(gAh, &Ah[w * 1024]);
    gload16(gAh + 512, &Ah[w * 1024 + 512]);
    gload16(gBh, &Bh[w * 1024]);
    gload16(gBh + 512, &Bh[w * 1024 + 512]);
    gload16(gBl, &Bl[w * 1024]);
    gload16(gBl + 512, &Bl[w * 1024 + 512]);
    __syncthreads();
    s16x8 ah[4], bh[4], bl[4];
#pragma unroll
    for (int g = 0; g < 4; ++g) {
      ah[g] = *reinterpret_cast<const s16x8*>(&Ah[(wr * 4 + g) * 512 + lane * 8]);
      bh[g] = *reinterpret_cast<const s16x8*>(&Bh[(wc * 4 + g) * 512 + lane * 8]);
      bl[g] = *reinterpret_cast<const s16x8*>(&Bl[(wc * 4 + g) * 512 + lane * 8]);
    }
#pragma unroll
    for (int rg = 0; rg < 4; ++rg)
#pragma unroll
      for (int cg = 0; cg < 4; ++cg) {
        acc[rg][cg] = __builtin_amdgcn_mfma_f32_16x16x32_bf16(ah[rg], bh[cg], acc[rg][cg], 0, 0, 0);
        acc[rg][cg] = __builtin_amdgcn_mfma_f32_16x16x32_bf16(ah[rg], bl[cg], acc[rg][cg], 0, 0, 0);
      }
    __syncthreads();
  }
  int r0 = b * 128;
  int qq = (lane >> 4) << 2;
#pragma unroll
  for (int rg = 0; rg < 4; ++rg) {
#pragma unroll
    for (int cg = 0; cg < 4; ++cg) {
      int colg = wc * 64 + cg * 16 + frow;
      float bv = bb[colg];
#pragma unroll
      for (int r = 0; r < 4; ++r) {
        int row = r0 + wr * 64 + rg * 16 + qq + r;
        if (row >= NN) continue;
        float val = acc[rg][cg][r] + bv;
        if (mat == 0)      qbf[(size_t)row * FHH + colg] = f2bf(val * QSCALE);
        else if (mat == 3) xsb[(size_t)row * FHH + colg] = f2bf(val);
        else {
          int pos = (colg >> 1) * 4 + ((mat == 2) ? 2 : 0) + (colg & 1);
          kv[(size_t)row * 256 + pos] = f2bf(val);
        }
      }
    }
  }
}

// ---------------- node-centric softmax aggregate ----------------
// 4 features/lane, 32 lanes per edge, two edges per wave (half-waves), unroll 8.
__global__ __launch_bounds__(256) void k_agg(const uint* __restrict__ qb,
                                             const ushort* __restrict__ kv,
                                             const uint* __restrict__ xsb,
                                             const int* __restrict__ row_ptr,
                                             const uint* __restrict__ colb,
                                             uint* __restrict__ yb) {
  int n = blockIdx.x * 4 + (threadIdx.x >> 6);
  int lane = threadIdx.x & 63;
  int hl = lane & 31, half = lane >> 5;
  uint2 qp = *reinterpret_cast<const uint2*>(qb + (n << 6) + 2 * hl);
#if !HAVE_BFDOT
  float qa = bfl(qp.x), qbv = bfh(qp.x), qc = bfl(qp.y), qd = bfh(qp.y);
#endif
  const char* kvb = (const char*)kv;
  uint tof = (uint)hl * 16u;
  int e0 = row_ptr[n], e1 = row_ptr[n + 1];
  float sum = 0.f, a0 = 0.f, a1 = 0.f, a2 = 0.f, a3 = 0.f;
  int i = e0;
#define QKDOT(d, p)                                                    \
  {                                                                    \
    p = qa * bfl(d.x);                                                 \
    p = fmaf(qbv, bfh(d.x), p);                                        \
    p = fmaf(qc, bfl(d.z), p);                                         \
    p = fmaf(qd, bfh(d.z), p);                                         \
  }
  for (; i + 8 <= e1; i += 8) {
    uint oA = colb[i + half] + tof;
    uint oB = colb[i + 2 + half] + tof;
    uint oC = colb[i + 4 + half] + tof;
    uint oD = colb[i + 6 + half] + tof;
    uint4 dA = *(const uint4*)(kvb + oA);
    uint4 dB = *(const uint4*)(kvb + oB);
    uint4 dC = *(const uint4*)(kvb + oC);
    uint4 dD = *(const uint4*)(kvb + oD);
    float pA, pB, pC, pD;
#if HAVE_BFDOT
    pA = dot2acc(dA.z, qp.y, dot2acc(dA.x, qp.x, 0.f));
    pB = dot2acc(dB.z, qp.y, dot2acc(dB.x, qp.x, 0.f));
    pC = dot2acc(dC.z, qp.y, dot2acc(dC.x, qp.x, 0.f));
    pD = dot2acc(dD.z, qp.y, dot2acc(dD.x, qp.x, 0.f));
#else
    QKDOT(dA, pA) QKDOT(dB, pB) QKDOT(dC, pC) QKDOT(dD, pD)
#endif
    pA += __shfl_xor(pA, 1, 4);  pB += __shfl_xor(pB, 1, 4);
    pC += __shfl_xor(pC, 1, 4);  pD += __shfl_xor(pD, 1, 4);
    pA += __shfl_xor(pA, 2, 4);  pB += __shfl_xor(pB, 2, 4);
    pC += __shfl_xor(pC, 2, 4);  pD += __shfl_xor(pD, 2, 4);
    float wA = exp2f(fminf(pA, 110.f));
    float wB = exp2f(fminf(pB, 110.f));
    float wC = exp2f(fminf(pC, 110.f));
    float wD = exp2f(fminf(pD, 110.f));
    sum += (wA + wB) + (wC + wD);
    a0 = fmaf(wA, bfl(dA.y), fmaf(wB, bfl(dB.y), fmaf(wC, bfl(dC.y), fmaf(wD, bfl(dD.y), a0))));
    a1 = fmaf(wA, bfh(dA.y), fmaf(wB, bfh(dB.y), fmaf(wC, bfh(dC.y), fmaf(wD, bfh(dD.y), a1))));
    a2 = fmaf(wA, bfl(dA.w), fmaf(wB, bfl(dB.w), fmaf(wC, bfl(dC.w), fmaf(wD, bfl(dD.w), a2))));
    a3 = fmaf(wA, bfh(dA.w), fmaf(wB, bfh(dB.w), fmaf(wC, bfh(dC.w), fmaf(wD, bfh(dD.w), a3))));
  }
  for (; i + 2 <= e1; i += 2) {
    uint oA = colb[i + half] + tof;
    uint4 dA = *(const uint4*)(kvb + oA);
    float pA;
#if HAVE_BFDOT
    pA = dot2acc(dA.z, qp.y, dot2acc(dA.x, qp.x, 0.f));
#else
    QKDOT(dA, pA)
#endif
    pA += __shfl_xor(pA, 1, 4);
    pA += __shfl_xor(pA, 2, 4);
    float wA = exp2f(fminf(pA, 110.f));
    sum += wA;
    a0 = fmaf(wA, bfl(dA.y), a0);
    a1 = fmaf(wA, bfh(dA.y), a1);
    a2 = fmaf(wA, bfl(dA.w), a2);
    a3 = fmaf(wA, bfh(dA.w), a3);
  }
  if (i < e1) {
    uint oA = colb[i] + tof;
    uint4 dA = *(const uint4*)(kvb + oA);
    float pA;
#if HAVE_BFDOT
    pA = dot2acc(dA.z, qp.y, dot2acc(dA.x, qp.x, 0.f));
#else
    QKDOT(dA, pA)
#endif
    pA += __shfl_xor(pA, 1, 4);
    pA += __shfl_xor(pA, 2, 4);
    float wA = exp2f(fminf(pA, 110.f));
    if (half) wA = 0.f;
    sum += wA;
    a0 = fmaf(wA, bfl(dA.y), a0);
    a1 = fmaf(wA, bfh(dA.y), a1);
    a2 = fmaf(wA, bfl(dA.w), a2);
    a3 = fmaf(wA, bfh(dA.w), a3);
  }
#undef QKDOT
  sum += __shfl_xor(sum, 32);
  a0 += __shfl_xor(a0, 32);
  a1 += __shfl_xor(a1, 32);
  a2 += __shfl_xor(a2, 32);
  a3 += __shfl_xor(a3, 32);
  float inv = 1.f / fmaxf(sum, 1e-16f);
  uint2 xv = *reinterpret_cast<const uint2*>(xsb + (n << 6) + 2 * hl);
  float o0 = fmaf(a0, inv, bfl(xv.x));
  float o1 = fmaf(a1, inv, bfh(xv.x));
  float o2 = fmaf(a2, inv, bfl(xv.y));
  float o3 = fmaf(a3, inv, bfh(xv.y));
  if (half == 0) {
    uint2 o;
    o.x = packbf(o0, o1);
    o.y = packbf(o2, o3);
    *reinterpret_cast<uint2*>(yb + (n << 6) + 2 * hl) = o;
  }
}

// ---------------- BN statistics (packed bf16 y) ----------------
__global__ __launch_bounds__(256) void k_bnstats(const uint* __restrict__ yb,
                                                 float* __restrict__ stats) {
  __shared__ float2 s1[256], s2[256];
  int u = threadIdx.x & 63;
  int grp = threadIdx.x >> 6;
  float2 a = make_float2(0.f, 0.f), b = make_float2(0.f, 0.f);
  for (int r = blockIdx.x * 4 + grp; r < NN; r += 1024) {
    uint d = yb[(size_t)r * 64 + u];
    float x = bfl(d), yv = bfh(d);
    a.x += x; a.y += yv;
    b.x = fmaf(x, x, b.x); b.y = fmaf(yv, yv, b.y);
  }
  s1[threadIdx.x] = a;
  s2[threadIdx.x] = b;
  __syncthreads();
  if (grp == 0) {
#pragma unroll
    for (int g = 1; g < 4; ++g) {
      a.x += s1[u + 64 * g].x; a.y += s1[u + 64 * g].y;
      b.x += s2[u + 64 * g].x; b.y += s2[u + 64 * g].y;
    }
    atomicAdd(&stats[2 * u], a.x);
    atomicAdd(&stats[2 * u + 1], a.y);
    atomicAdd(&stats[128 + 2 * u], b.x);
    atomicAdd(&stats[128 + 2 * u + 1], b.y);
  }
}

// ---------------- fused post: BN+ReLU once -> (pool atomic means) + (bf16-high fragment write) ----
template <int WRITE_X>
__global__ __launch_bounds__(256) void k_post(const uint* __restrict__ yb,
                                              const float* __restrict__ st,
                                              const float* __restrict__ gvec,
                                              const float* __restrict__ bvec_,
                                              const int* __restrict__ bv,
                                              const int* __restrict__ gstart,
                                              float* __restrict__ out, int layer,
                                              ushort* __restrict__ Xh) {
  __shared__ float acts[8][128];
  __shared__ int sg[8];
  __shared__ float ssc[128], ssh[128];
  int b = blockIdx.x, t = threadIdx.x;
  if (t < 128) {
    const float invn = 1.f / (float)NN;
    float mu = st[t] * invn;
    float var = st[128 + t] * invn - mu * mu;
    float sc = gvec[t] * rsqrtf(var + 1e-5f);
    ssc[t] = sc;
    ssh[t] = bvec_[t] - mu * sc;
  }
  if (t < 8) sg[t] = (b * 8 + t < NN) ? bv[b * 8 + t] : -1;
  __syncthreads();
  int row = b * 8 + (t >> 5);
  int c4 = (t & 31) * 4;
  bool ok = row < NN;
  float4 a = make_float4(0.f, 0.f, 0.f, 0.f);
  if (ok) {
    uint2 u2 = *reinterpret_cast<const uint2*>(yb + (size_t)row * 64 + (c4 >> 1));
    a.x = fmaxf(fmaf(bfl(u2.x), ssc[c4 + 0], ssh[c4 + 0]), 0.f);
    a.y = fmaxf(fmaf(bfh(u2.x), ssc[c4 + 1], ssh[c4 + 1]), 0.f);
    a.z = fmaxf(fmaf(bfl(u2.y), ssc[c4 + 2], ssh[c4 + 2]), 0.f);
    a.w = fmaxf(fmaf(bfh(u2.y), ssc[c4 + 3], ssh[c4 + 3]), 0.f);
  }
  *reinterpret_cast<float4*>(&acts[t >> 5][c4]) = a;
  if (WRITE_X && ok) {
    ushort h0 = f2bf(a.x), h1 = f2bf(a.y), h2 = f2bf(a.z), h3 = f2bf(a.w);
    int bb = row >> 7, g = (row & 127) >> 4, frow = row & 15;
    int ks = c4 >> 5, qq = (c4 & 31) >> 3, j = c4 & 7;
    size_t base = ((size_t)ks * NB + bb) * 4096 + (((g * 4 + qq) * 16) + frow) * 8 + j;
    *reinterpret_cast<uint2*>(Xh + base) =
        make_uint2((uint)h0 | ((uint)h1 << 16), (uint)h2 | ((uint)h3 << 16));
  }
  __syncthreads();
  if (t < 128) {
    float racc = 0.f;
    int cg = sg[0];
    for (int r = 0; r < 8; ++r) {
      int g = sg[r];
      if (g != cg) {
        if (cg >= 0) {
          float p = racc / (float)(gstart[cg + 1] - gstart[cg]);
          if (layer < 5) atomicAdd(&out[(size_t)cg * 1024 + layer * FHH + t], p);
          else {
            atomicAdd(&out[(size_t)cg * 1024 + 5 * FHH + t], p);
            atomicAdd(&out[(size_t)cg * 1024 + 6 * FHH + t], p);
            atomicAdd(&out[(size_t)cg * 1024 + 7 * FHH + t], p);
          }
        }
        racc = 0.f;
        cg = g;
      }
      racc += acts[r][t];
    }
    if (cg >= 0) {
      float p = racc / (float)(gstart[cg + 1] - gstart[cg]);
      if (layer < 5) atomicAdd(&out[(size_t)cg * 1024 + layer * FHH + t], p);
      else {
        atomicAdd(&out[(size_t)cg * 1024 + 5 * FHH + t], p);
        atomicAdd(&out[(size_t)cg * 1024 + 6 * FHH + t], p);
        atomicAdd(&out[(size_t)cg * 1024 + 7 * FHH + t], p);
      }
    }
  }
}

extern "C" void kernel_launch(void* const* d_in, const int* in_sizes, int n_in,
                              void* d_out, int out_size, void* d_ws, size_t ws_size,
                              hipStream_t stream) {
  (void)in_sizes; (void)n_in; (void)ws_size;
  const float* x    = (const float*)d_in[0];
  const int*   ei   = (const int*)d_in[1];
  const int*   bvec = (const int*)d_in[2];
  const float* Wq0  = (const float*)d_in[3];
  const float* bq0  = (const float*)d_in[4];
  const float* Wk0  = (const float*)d_in[5];
  const float* bk0  = (const float*)d_in[6];
  const float* Wv0  = (const float*)d_in[7];
  const float* bv0  = (const float*)d_in[8];
  const float* Ws0  = (const float*)d_in[9];
  const float* bs0  = (const float*)d_in[10];
  const float* WqS  = (const float*)d_in[11];
  const float* bqS  = (const float*)d_in[12];
  const float* WkS  = (const float*)d_in[13];
  const float* bkS  = (const float*)d_in[14];
  const float* WvS  = (const float*)d_in[15];
  const float* bvS  = (const float*)d_in[16];
  const float* WsS  = (const float*)d_in[17];
  const float* bsS  = (const float*)d_in[18];
  const float* gamma = (const float*)d_in[19];
  const float* beta  = (const float*)d_in[20];
  float* out = (float*)d_out;

  char* ws = (char*)d_ws;
  size_t off = 0;
  auto alloc = [&](size_t bytes) {
    void* p = ws + off;
    off = (off + bytes + 255) & ~(size_t)255;
    return p;
  };
  ushort* qbf = (ushort*)alloc((size_t)NN * FHH * 2);
  ushort* xsb = (ushort*)alloc((size_t)NN * FHH * 2);
  uint* yb    = (uint*)alloc((size_t)NN * 64 * 4);
  ushort* kv  = (ushort*)alloc((size_t)NN * 256 * 2);
  ushort* Xh  = (ushort*)alloc((size_t)4 * NB * 4096 * 2 + 8192);
  uint* colb   = (uint*)alloc((size_t)NE * 4);
  int* row_ptr = (int*)alloc((size_t)(NN + 1) * 4);
  int* cursor  = (int*)alloc((size_t)NN * 4);
  int* deg     = (int*)alloc((size_t)NN * 4);
  int* part    = (int*)alloc((size_t)NCH * 4);
  int* gstart  = (int*)alloc((size_t)(NG + 1) * 4);
  float* bstat = (float*)alloc((size_t)NL * 2 * FHH * 4);   // [layer][{sum,sumsq}][128]
  ushort* wsh = (ushort*)alloc((size_t)360448 * 2);
  ushort* wsl = (ushort*)alloc((size_t)360448 * 2);

  const int* srcv = ei;
  const int* dstv = ei + NE;

  hipMemsetAsync(out, 0, (size_t)out_size * 4, stream);
  hipMemsetAsync(deg, 0, (size_t)NN * 4, stream);
  hipMemsetAsync(bstat, 0, (size_t)NL * 2 * FHH * 4, stream);
  k_gstart<<<5, 64, 0, stream>>>(bvec, gstart);
  k_deg<<<(NE + 255) / 256, 256, 0, stream>>>(dstv, deg);
  k_scanA<<<NCH, 256, 0, stream>>>(deg, part);
  k_scanB<<<1, 64, 0, stream>>>(part, row_ptr);
  k_scanC<<<NCH, 1024, 0, stream>>>(deg, part, row_ptr, cursor);
  k_scatter<<<(NE + 255) / 256, 256, 0, stream>>>(srcv, dstv, cursor, colb);
  k_wconv0<<<128, 256, 0, stream>>>(Wq0, Wk0, Wv0, Ws0, wsh, wsl);
  k_wconvS<<<1280, 256, 0, stream>>>(WqS, WkS, WvS, WsS, wsh, wsl);
  k_presplit<64><<<(NN * 16 + 255) / 256, 256, 0, stream>>>(x, Xh);

  const int GEMM_GRID = 49 * 32;   // ceil(NB/8)*32 : 4 mats x NB blocks, XCD-swizzled
  for (int l = 0; l < NL; ++l) {
    const ushort* WthL = wsh + ((l == 0) ? 0 : (size_t)32768 + (size_t)(l - 1) * 65536);
    const ushort* WtlL = wsl + ((l == 0) ? 0 : (size_t)32768 + (size_t)(l - 1) * 65536);
    const float *bq_, *bk_, *bv_, *bs_;
    if (l == 0) { bq_ = bq0; bk_ = bk0; bv_ = bv0; bs_ = bs0; }
    else {
      size_t bo = (size_t)(l - 1) * FHH;
      bq_ = bqS + bo; bk_ = bkS + bo; bv_ = bvS + bo; bs_ = bsS + bo;
    }
    if (l == 0)
      k_gemm<64><<<GEMM_GRID, 256, 0, stream>>>(Xh, WthL, WtlL, bq_, bk_, bv_, bs_, qbf, kv, xsb);
    else
      k_gemm<128><<<GEMM_GRID, 256, 0, stream>>>(Xh, WthL, WtlL, bq_, bk_, bv_, bs_, qbf, kv, xsb);
    k_agg<<<NN / 4, 256, 0, stream>>>((const uint*)qbf, kv, (const uint*)xsb, row_ptr, colb, yb);
    float* lstat = bstat + (size_t)l * 2 * FHH;
    k_bnstats<<<256, 256, 0, stream>>>(yb, lstat);
    if (l + 1 < NL)
      k_post<1><<<6250, 256, 0, stream>>>(yb, lstat, gamma + (size_t)l * FHH,
                                          beta + (size_t)l * FHH, bvec, gstart, out, l, Xh);
    else
      k_post<0><<<6250, 256, 0, stream>>>(yb, lstat, gamma + (size_t)l * FHH,
                                          beta + (size_t)l * FHH, bvec, gstart, out, l, Xh);
  }
}